// Round 8
// baseline (750.703 us; speedup 1.0000x reference)
//
#include <hip/hip_runtime.h>
#include <cstdint>
#include <cstddef>

typedef unsigned short u16;
typedef unsigned int u32;
typedef short bf16x8 __attribute__((ext_vector_type(8)));
typedef unsigned short u16x4 __attribute__((ext_vector_type(4)));
typedef unsigned short u16x8 __attribute__((ext_vector_type(8)));
typedef float f32x4 __attribute__((ext_vector_type(4)));
typedef float f32x16 __attribute__((ext_vector_type(16)));

#define DEV __device__ __forceinline__

// ---------- constants ----------
constexpr int Bb = 4, Tt = 1024, Cc = 2048, Hh = 32, Nd = 64, FF = 7168;
constexpr int BT = Bb * Tt; // 4096
constexpr int NCH = 16;     // chunks of 64

// ---------- helpers ----------
DEV u16 f2bf(float f) {
  union { float f; unsigned u; } un; un.f = f;
  unsigned r = un.u + 0x7FFFu + ((un.u >> 16) & 1u);
  return (u16)(r >> 16);
}
DEV float bf2f(u16 h) {
  union { unsigned u; float f; } un; un.u = ((unsigned)h) << 16;
  return un.f;
}
DEV void gll16(const u16* gp, u16* lp) {
  __builtin_amdgcn_global_load_lds(
      (const __attribute__((address_space(1))) unsigned int*)gp,
      (__attribute__((address_space(3))) unsigned int*)lp,
      16, 0, 0);
}
// XCD-bijective swizzle: each XCD (f%8) owns a contiguous chunk of tile order.
DEV int xcd_swz(int f, int nwg) {
  int q = nwg >> 3;
  return (f & 7) * q + (f >> 3);
}

// ---------- transpose + f32->bf16: W[Kk][Nn] -> Wt[Nn][Kk], 64x64 tiles ----------
DEV void transp64_body(const float* __restrict__ W, u16* __restrict__ Wt,
                       int Kk, int Nn) {
  const int n0 = blockIdx.x * 64, k0 = blockIdx.y * 64;
  const int tx = threadIdx.x & 15, ty = threadIdx.x >> 4;
  const int kk = k0 + ty * 4, nn = n0 + tx * 4;
  const float* p = W + (size_t)kk * Nn + nn;
  f32x4 r0 = *(const f32x4*)(p);
  f32x4 r1 = *(const f32x4*)(p + (size_t)Nn);
  f32x4 r2 = *(const f32x4*)(p + 2 * (size_t)Nn);
  f32x4 r3 = *(const f32x4*)(p + 3 * (size_t)Nn);
  #pragma unroll
  for (int j = 0; j < 4; j++) {
    u16x4 o;
    o[0] = f2bf(r0[j]); o[1] = f2bf(r1[j]); o[2] = f2bf(r2[j]); o[3] = f2bf(r3[j]);
    *(u16x4*)(Wt + (size_t)(nn + j) * Kk + kk) = o;
  }
}

__global__ void transp64(const float* __restrict__ W, u16* __restrict__ Wt,
                         int Kk, int Nn) {
  transp64_body(W, Wt, Kk, Nn);
}

__global__ void transp64_6cc(const float* __restrict__ W0, const float* __restrict__ W1,
                             const float* __restrict__ W2, const float* __restrict__ W3,
                             const float* __restrict__ W4, const float* __restrict__ W5,
                             u16* __restrict__ T0, u16* __restrict__ T1,
                             u16* __restrict__ T2, u16* __restrict__ T3,
                             u16* __restrict__ T4, u16* __restrict__ T5) {
  const int z = blockIdx.z;
  const float* W = (z == 0) ? W0 : (z == 1) ? W1 : (z == 2) ? W2 :
                   (z == 3) ? W3 : (z == 4) ? W4 : W5;
  u16* T = (z == 0) ? T0 : (z == 1) ? T1 : (z == 2) ? T2 :
           (z == 3) ? T3 : (z == 4) ? T4 : T5;
  transp64_body(W, T, Cc, Cc);
}

// ---------- block LayerNorm stats helper ----------
DEV void block_ln(const float* __restrict__ src, int tid, float* red,
                  float vals[8], float& mean, float& inv) {
  float s = 0.f, ss = 0.f;
  #pragma unroll
  for (int i = 0; i < 8; i++) {
    float t = src[tid + i * 256];
    vals[i] = t; s += t; ss += t * t;
  }
  #pragma unroll
  for (int m = 1; m < 64; m <<= 1) { s += __shfl_xor(s, m); ss += __shfl_xor(ss, m); }
  int lane = tid & 63, wv = tid >> 6;
  __syncthreads();
  if (lane == 0) { red[wv] = s; red[4 + wv] = ss; }
  __syncthreads();
  s = red[0] + red[1] + red[2] + red[3];
  ss = red[4] + red[5] + red[6] + red[7];
  mean = s * (1.f / Cc);
  float var = ss * (1.f / Cc) - mean * mean;
  inv = rsqrtf(var + 1e-5f);
}

// ---------- fused LN + 4-way mix ----------
__global__ __launch_bounds__(256)
void ln_mix4(const float* __restrict__ x, const float* __restrict__ shift,
             const float* __restrict__ w, const float* __restrict__ b,
             const float* __restrict__ mk, const float* __restrict__ mv,
             const float* __restrict__ mr, const float* __restrict__ mg,
             u16* __restrict__ xk, u16* __restrict__ xv,
             u16* __restrict__ xr, u16* __restrict__ xg,
             float* __restrict__ last) {
  int row = blockIdx.x;
  int t = row & (Tt - 1), bb = row >> 10;
  int tid = threadIdx.x;
  __shared__ float red[8];
  const float* cur = x + (size_t)row * Cc;
  float cv[8], pv[8], cm, ci, pm = 0.f, pi = 1.f;
  block_ln(cur, tid, red, cv, cm, ci);
  bool t0 = (t == 0);
  const float* prev = t0 ? (shift + (size_t)bb * Cc) : (cur - Cc);
  if (!t0) {
    block_ln(prev, tid, red, pv, pm, pi);
  } else {
    #pragma unroll
    for (int i = 0; i < 8; i++) pv[i] = prev[tid + i * 256];
  }
  size_t o = (size_t)row * Cc;
  bool isLast = (t == Tt - 1);
  #pragma unroll
  for (int i = 0; i < 8; i++) {
    int c = tid + i * 256;
    float xc = (cv[i] - cm) * ci * w[c] + b[c];
    float xp = t0 ? pv[i] : (pv[i] - pm) * pi * w[c] + b[c];
    xk[o + c] = f2bf(xp + mk[c] * (xc - xp));
    xv[o + c] = f2bf(xp + mv[c] * (xc - xp));
    xr[o + c] = f2bf(xp + mr[c] * (xc - xp));
    xg[o + c] = f2bf(xp + mg[c] * (xc - xp));
    if (isLast) last[(size_t)bb * Cc + c] = xc;
  }
}

// ---------- fused LN + 2-way mix ----------
__global__ __launch_bounds__(256)
void ln_mix2(const float* __restrict__ x, const float* __restrict__ shift,
             const float* __restrict__ w, const float* __restrict__ b,
             const float* __restrict__ ck, const float* __restrict__ cr,
             u16* __restrict__ xck, u16* __restrict__ xcr,
             float* __restrict__ last) {
  int row = blockIdx.x;
  int t = row & (Tt - 1), bb = row >> 10;
  int tid = threadIdx.x;
  __shared__ float red[8];
  const float* cur = x + (size_t)row * Cc;
  float cv[8], pv[8], cm, ci, pm = 0.f, pi = 1.f;
  block_ln(cur, tid, red, cv, cm, ci);
  bool t0 = (t == 0);
  const float* prev = t0 ? (shift + (size_t)bb * Cc) : (cur - Cc);
  if (!t0) {
    block_ln(prev, tid, red, pv, pm, pi);
  } else {
    #pragma unroll
    for (int i = 0; i < 8; i++) pv[i] = prev[tid + i * 256];
  }
  size_t o = (size_t)row * Cc;
  bool isLast = (t == Tt - 1);
  #pragma unroll
  for (int i = 0; i < 8; i++) {
    int c = tid + i * 256;
    float xc = (cv[i] - cm) * ci * w[c] + b[c];
    float xp = t0 ? pv[i] : (pv[i] - pm) * pi * w[c] + b[c];
    xck[o + c] = f2bf(xp + ck[c] * (xc - xp));
    xcr[o + c] = f2bf(xp + cr[c] * (xc - xp));
    if (isLast) last[(size_t)bb * Cc + c] = xc;
  }
}

// ====== 256xBN deep-pipelined GEMM (8-wave, BK=64, 32x32x16 MFMA, 2 phases) ======
DEV int swzoff(int row, int off) {
  return (row << 7) +
         (off ^ ((((row >> 1) & 1) << 4) | (((row >> 2) & 1) << 5) | (((row >> 3) & 1) << 6)));
}

DEV void stage_half(const u16* __restrict__ gbase, int ldK, u16* slot, int tid) {
  #pragma unroll
  for (int c2 = 0; c2 < 2; c2++) {
    const int D = c2 * 8192 + tid * 16;
    const int row = D >> 7;
    const int off = (D & 127) ^ ((((row >> 1) & 1) << 4) | (((row >> 2) & 1) << 5) | (((row >> 3) & 1) << 6));
    gll16(gbase + (size_t)row * ldK + (off >> 1), (u16*)((char*)slot + D));
  }
}

// EPI: 0=f32, 1=bf16(+act silu), 3=relu^2->bf16, 4=X1+val->f32,
//      6=X1+sigmoid(val)*(X2+bf2f(X2b))->f32
template <int EPI, int NB>
DEV void g256_core(const u16* __restrict__ A, const u16* __restrict__ Bt,
                   int N, int K, int ldK,
                   float* __restrict__ Co, u16* __restrict__ Cb,
                   const float* __restrict__ X1, const float* __restrict__ X2,
                   const u16* __restrict__ X2b,
                   u16 (*lds)[8192], int m0, int n0, int act) {
  const int tid = threadIdx.x;
  const int w = tid >> 6, lane = tid & 63;
  const int l31 = lane & 31, l5 = lane >> 5;
  const int wm = (w & 3) * 64;
  const int wn = (w >> 2) * (NB * 64);
  const int ahalf = wm >> 7;
  const int arow0 = wm & 127;
  const int bhalf = (NB == 2) ? (w >> 2) : 0;
  const int nt = K >> 6;

  const u16* Ag = A + (size_t)m0 * ldK;
  const u16* Bg = Bt + (size_t)n0 * ldK;

  f32x16 acc[2][2 * NB] = {};   // [mf][global nf]
  bf16x8 a[2][4];               // [mf][ks], live across both phases

  // ---- prologue: tile0 A+B, tile1 A ----
  stage_half(Ag, ldK, lds[0], tid);
  stage_half(Ag + (size_t)128 * ldK, ldK, lds[1], tid);
  stage_half(Bg, ldK, lds[4], tid);
  if constexpr (NB == 2) stage_half(Bg + (size_t)128 * ldK, ldK, lds[5], tid);
  if (nt > 1) {
    stage_half(Ag + 64, ldK, lds[2], tid);
    stage_half(Ag + (size_t)128 * ldK + 64, ldK, lds[3], tid);
    asm volatile("s_waitcnt vmcnt(4)" ::: "memory");
  } else {
    asm volatile("s_waitcnt vmcnt(0)" ::: "memory");
  }
  asm volatile("s_barrier" ::: "memory");

  for (int t = 0; t < nt; t++) {
    const int buf = t & 1;
    const char* Aslot = (const char*)lds[buf * 2 + ahalf];
    const char* Bslot = (const char*)lds[4 + buf * NB + bhalf];

    // ---------- phase 0: A frags + B(nh=0) frags ; stage B(t+1) ----------
    #pragma unroll
    for (int mf = 0; mf < 2; mf++)
      #pragma unroll
      for (int ks = 0; ks < 4; ks++)
        a[mf][ks] = *(const bf16x8*)(Aslot + swzoff(arow0 + mf * 32 + l31, ks * 32 + l5 * 16));
    {
      bf16x8 b[NB][4];
      #pragma unroll
      for (int nf = 0; nf < NB; nf++)
        #pragma unroll
        for (int ks = 0; ks < 4; ks++)
          b[nf][ks] = *(const bf16x8*)(Bslot +
              swzoff((NB == 2 ? 0 : wn) + nf * 32 + l31, ks * 32 + l5 * 16));
      if (t + 1 < nt) {
        stage_half(Bg + (size_t)(t + 1) * 64, ldK, lds[4 + ((t + 1) & 1) * NB], tid);
        if constexpr (NB == 2)
          stage_half(Bg + (size_t)128 * ldK + (size_t)(t + 1) * 64, ldK,
                     lds[4 + ((t + 1) & 1) * NB + 1], tid);
      }
      asm volatile("s_barrier" ::: "memory");
      __builtin_amdgcn_s_setprio(1);
      #pragma unroll
      for (int mf = 0; mf < 2; mf++)
        #pragma unroll
        for (int nf = 0; nf < NB; nf++)
          #pragma unroll
          for (int ks = 0; ks < 4; ks++)
            acc[mf][nf] = __builtin_amdgcn_mfma_f32_32x32x16_bf16(
                a[mf][ks], b[nf][ks], acc[mf][nf], 0, 0, 0);
      __builtin_amdgcn_s_setprio(0);
      asm volatile("s_barrier" ::: "memory");
    }
    // ---------- phase 1: B(nh=1) frags ; stage A(t+2) ----------
    {
      bf16x8 b[NB][4];
      #pragma unroll
      for (int nf = 0; nf < NB; nf++)
        #pragma unroll
        for (int ks = 0; ks < 4; ks++)
          b[nf][ks] = *(const bf16x8*)(Bslot +
              swzoff((NB == 2 ? 0 : wn) + (NB + nf) * 32 + l31, ks * 32 + l5 * 16));
      if (t + 2 < nt) {
        stage_half(Ag + (size_t)(t + 2) * 64, ldK, lds[buf << 1], tid);
        stage_half(Ag + (size_t)128 * ldK + (size_t)(t + 2) * 64, ldK,
                   lds[(buf << 1) + 1], tid);
      }
      asm volatile("s_barrier" ::: "memory");
      __builtin_amdgcn_s_setprio(1);
      #pragma unroll
      for (int mf = 0; mf < 2; mf++)
        #pragma unroll
        for (int nf = 0; nf < NB; nf++)
          #pragma unroll
          for (int ks = 0; ks < 4; ks++)
            acc[mf][NB + nf] = __builtin_amdgcn_mfma_f32_32x32x16_bf16(
                a[mf][ks], b[nf][ks], acc[mf][NB + nf], 0, 0, 0);
      __builtin_amdgcn_s_setprio(0);
      if (t + 2 < nt) asm volatile("s_waitcnt vmcnt(4)" ::: "memory");
      else            asm volatile("s_waitcnt vmcnt(0)" ::: "memory");
      asm volatile("s_barrier" ::: "memory");
    }
  }

  // ---- epilogue: C/D layout col=lane&31, row=(reg&3)+8*(reg>>2)+4*(lane>>5) ----
  #pragma unroll
  for (int mf = 0; mf < 2; mf++) {
    #pragma unroll
    for (int reg = 0; reg < 16; reg++) {
      const int gr = m0 + wm + mf * 32 + (reg & 3) + 8 * (reg >> 2) + 4 * l5;
      const size_t ro = (size_t)gr * N;
      #pragma unroll
      for (int nf = 0; nf < 2 * NB; nf++) {
        const int gc = n0 + wn + nf * 32 + l31;
        float val = acc[mf][nf][reg];
        if constexpr (EPI == 0) {
          Co[ro + gc] = val;
        } else if constexpr (EPI == 1) {
          if (act) val = val / (1.f + __expf(-val));
          Cb[ro + gc] = f2bf(val);
        } else if constexpr (EPI == 3) {
          float tr = fmaxf(val, 0.f);
          Cb[ro + gc] = f2bf(tr * tr);
        } else if constexpr (EPI == 4) {
          Co[ro + gc] = X1[ro + gc] + val;
        } else {
          float s = 1.f / (1.f + __expf(-val));
          float kvv = X2[ro + gc] + bf2f(X2b[ro + gc]);
          Co[ro + gc] = fmaf(s, kvv, X1[ro + gc]);
        }
      }
    }
  }
}

// BN=256 swizzled wrapper (grid 1D, nwg%8==0; tile order: x fastest over NX)
template <int EPI>
__global__ __launch_bounds__(512)
void gemm256s(const u16* __restrict__ A, const u16* __restrict__ Bt,
              int N, int K,
              float* __restrict__ Co, u16* __restrict__ Cb,
              const float* __restrict__ X1, int NX) {
  __shared__ __align__(16) u16 lds[8][8192];
  int o = xcd_swz(blockIdx.x, gridDim.x);
  int xb = o % NX, yb = o / NX;
  g256_core<EPI, 2>(A, Bt, N, K, K, Co, Cb, X1, nullptr, nullptr, lds,
                    yb * 256, xb * 256, 0);
}

// BN=128 swizzled wrapper
template <int EPI>
__global__ __launch_bounds__(512)
void gemm128s(const u16* __restrict__ A, const u16* __restrict__ Bt,
              int N, int K,
              float* __restrict__ Co, u16* __restrict__ Cb,
              const float* __restrict__ X1, const float* __restrict__ X2,
              const u16* __restrict__ X2b, int NX) {
  __shared__ __align__(16) u16 lds[6][8192];
  int o = xcd_swz(blockIdx.x, gridDim.x);
  int xb = o % NX, yb = o / NX;
  g256_core<EPI, 1>(A, Bt, N, K, K, Co, Cb, X1, X2, X2b, lds,
                    yb * 256, xb * 128, 0);
}

// projection GEMMs: grid 1D = 8*16*4, swizzled
__global__ __launch_bounds__(512)
void gemm256_proj(const u16* __restrict__ A0, const u16* __restrict__ A1,
                  const u16* __restrict__ A2, const u16* __restrict__ A3,
                  const u16* __restrict__ B0, const u16* __restrict__ B1,
                  const u16* __restrict__ B2, const u16* __restrict__ B3,
                  u16* __restrict__ C0, u16* __restrict__ C1,
                  u16* __restrict__ C2, u16* __restrict__ C3) {
  __shared__ __align__(16) u16 lds[8][8192];
  int o = xcd_swz(blockIdx.x, gridDim.x);
  int xb = o & 7, yb = (o >> 3) & 15, z = o >> 7;
  const u16* A = (z == 0) ? A0 : (z == 1) ? A1 : (z == 2) ? A2 : A3;
  const u16* Bt = (z == 0) ? B0 : (z == 1) ? B1 : (z == 2) ? B2 : B3;
  u16* Cb = (z == 0) ? C0 : (z == 1) ? C1 : (z == 2) ? C2 : C3;
  g256_core<1, 2>(A, Bt, Cc, Cc, Cc, nullptr, Cb, nullptr, nullptr, nullptr, lds,
                  yb * 256, xb * 256, z == 3);
}

// split-K=2 Wcv GEMM: z=0 -> f32 partial kv0; z=1 -> bf16 partial kv1.
__global__ __launch_bounds__(512)
void gemm256_splitk(const u16* __restrict__ A, const u16* __restrict__ Bt,
                    float* __restrict__ kv0, u16* __restrict__ kv1) {
  __shared__ __align__(16) u16 lds[8][8192];
  int o = xcd_swz(blockIdx.x, gridDim.x);
  int xb = o & 7, yb = (o >> 3) & 15, z = o >> 7;
  const int Koff = z * (FF / 2);
  if (z == 0)
    g256_core<0, 2>(A + Koff, Bt + Koff, Cc, FF / 2, FF, kv0, nullptr,
                    nullptr, nullptr, nullptr, lds, yb * 256, xb * 256, 0);
  else
    g256_core<1, 2>(A + Koff, Bt + Koff, Cc, FF / 2, FF, nullptr, kv1,
                    nullptr, nullptr, nullptr, lds, yb * 256, xb * 256, 0);
}

// ======================= chunked WKV : three kernels =======================
__global__ __launch_bounds__(256)
void wkv_pre(const u16* __restrict__ rg, const u16* __restrict__ kg,
             const u16* __restrict__ vg, const float* __restrict__ td,
             const float* __restrict__ tf,
             float* __restrict__ Yb, float* __restrict__ Db,
             u16* __restrict__ Rtb) {
  __shared__ float Pt[64][68];
  __shared__ float uL[64];
  __shared__ u16 rB[64 * 72];
  __shared__ u16 kB[64 * 72];
  __shared__ u16 Rh[64 * 72];
  __shared__ u16 KhX[96 * 72];
  __shared__ u16 vA[64 * 72];
  __shared__ u16 Vt[64 * 72];

  const int tid = threadIdx.x, bid = blockIdx.x;
  const int bh = bid >> 4, c = bid & 15;
  const int b = bh >> 5, h = bh & 31;
  const int lane = tid & 63, w = tid >> 6;

  {
    int i = tid & 63;
    float d = __expf(td[h * 64 + i]);
    float c1 = -1.4426950408889634f * d;
    int e0 = (tid >> 6) * 16;
    #pragma unroll
    for (int e = 0; e < 16; e++) Pt[e0 + e][i] = exp2f(c1 * (float)(e0 + e));
    if (tid < 64) uL[tid] = tf[h * 64 + tid];
  }
  __syncthreads();

  const int row = tid >> 2, col0 = (tid & 3) * 16;
  const int tl = row & 15;
  {
    size_t gro = ((size_t)b * Tt + c * 64 + row) * Cc + h * 64 + col0;
    u16x8 rv0 = *(const u16x8*)(rg + gro);
    u16x8 rv1 = *(const u16x8*)(rg + gro + 8);
    u16x8 kv0 = *(const u16x8*)(kg + gro);
    u16x8 kv1 = *(const u16x8*)(kg + gro + 8);
    u16x8 vv0 = *(const u16x8*)(vg + gro);
    u16x8 vv1 = *(const u16x8*)(vg + gro + 8);
    *(u16x8*)&rB[row * 72 + col0] = rv0; *(u16x8*)&rB[row * 72 + col0 + 8] = rv1;
    *(u16x8*)&kB[row * 72 + col0] = kv0; *(u16x8*)&kB[row * 72 + col0 + 8] = kv1;
    *(u16x8*)&vA[row * 72 + col0] = vv0; *(u16x8*)&vA[row * 72 + col0 + 8] = vv1;
    float rf[16], kf[16];
    #pragma unroll
    for (int e = 0; e < 8; e++) { rf[e] = bf2f(rv0[e]); rf[8 + e] = bf2f(rv1[e]); }
    #pragma unroll
    for (int e = 0; e < 8; e++) { kf[e] = bf2f(kv0[e]); kf[8 + e] = bf2f(kv1[e]); }
    u16x8 o0, o1, t0_, t1_;
    #pragma unroll
    for (int e = 0; e < 8; e++) {
      o0[e] = f2bf(rf[e] * Pt[tl][col0 + e]);
      o1[e] = f2bf(rf[8 + e] * Pt[tl][col0 + 8 + e]);
      t0_[e] = f2bf(rf[e] * Pt[row][col0 + e]);
      t1_[e] = f2bf(rf[8 + e] * Pt[row][col0 + 8 + e]);
    }
    *(u16x8*)&Rh[row * 72 + col0] = o0; *(u16x8*)&Rh[row * 72 + col0 + 8] = o1;
    u16* rtp = Rtb + (size_t)bid * 4096 + row * 64 + col0;
    *(u16x8*)rtp = t0_; *(u16x8*)(rtp + 8) = t1_;
    if (row < 48) {
      u16x8 a0, a1;
      #pragma unroll
      for (int e = 0; e < 8; e++) {
        a0[e] = f2bf(kf[e] * Pt[15 - tl][col0 + e]);
        a1[e] = f2bf(kf[8 + e] * Pt[15 - tl][col0 + 8 + e]);
      }
      *(u16x8*)&KhX[row * 72 + col0] = a0; *(u16x8*)&KhX[row * 72 + col0 + 8] = a1;
    }
    if (row < 32) {
      u16x8 a0, a1;
      #pragma unroll
      for (int e = 0; e < 8; e++) {
        a0[e] = f2bf(kf[e] * Pt[31 - tl][col0 + e]);
        a1[e] = f2bf(kf[8 + e] * Pt[31 - tl][col0 + 8 + e]);
      }
      *(u16x8*)&KhX[(48 + row) * 72 + col0] = a0; *(u16x8*)&KhX[(48 + row) * 72 + col0 + 8] = a1;
    }
    if (row < 16) {
      u16x8 a0, a1;
      #pragma unroll
      for (int e = 0; e < 8; e++) {
        a0[e] = f2bf(kf[e] * Pt[47 - tl][col0 + e]);
        a1[e] = f2bf(kf[8 + e] * Pt[47 - tl][col0 + 8 + e]);
      }
      *(u16x8*)&KhX[(80 + row) * 72 + col0] = a0; *(u16x8*)&KhX[(80 + row) * 72 + col0 + 8] = a1;
    }
  }
  __syncthreads();

  {
    const int jj = tid & 63, s0 = (tid >> 6) * 16;
    #pragma unroll
    for (int ds = 0; ds < 16; ds += 2) {
      u32 pk = ((u32)vA[(s0 + ds + 1) * 72 + jj] << 16) | vA[(s0 + ds) * 72 + jj];
      *(u32*)&Vt[jj * 72 + s0 + ds] = pk;
    }
  }
  __syncthreads();

  u16* aB = vA;
  {
    const int pr[6] = {1, 2, 3, 2, 3, 3};
    const int qr[6] = {0, 1, 2, 0, 1, 0};
    const int dr[6] = {0, 0, 0, 1, 1, 2};
    const int lr = lane & 15, kq = lane >> 4;
    for (int pi = w; pi < 6; pi += 4) {
      const int p = pr[pi], q = qr[pi], d = dr[pi];
      const int kbase = (d == 0) ? q * 16 : (d == 1) ? 48 + q * 16 : 80 + q * 16;
      f32x4 aacc = {};
      #pragma unroll
      for (int kf2 = 0; kf2 < 2; kf2++) {
        bf16x8 af = *(const bf16x8*)&Rh[(p * 16 + lr) * 72 + kf2 * 32 + kq * 8];
        bf16x8 bf_ = *(const bf16x8*)&KhX[(kbase + lr) * 72 + kf2 * 32 + kq * 8];
        aacc = __builtin_amdgcn_mfma_f32_16x16x32_bf16(af, bf_, aacc, 0, 0, 0);
      }
      #pragma unroll
      for (int reg = 0; reg < 4; reg++) {
        aB[(p * 16 + kq * 4 + reg) * 72 + q * 16 + lr] = f2bf(aacc[reg]);
        aB[(q * 16 + kq * 4 + reg) * 72 + p * 16 + lr] = 0;
      }
    }
    for (int e = lane; e < 256; e += 64) {
      const int tl2 = e >> 4, sl = e & 15;
      float a = 0.f;
      if (sl <= tl2) {
        const u16* rp = &rB[(w * 16 + tl2) * 72];
        const u16* kp = &kB[(w * 16 + sl) * 72];
        const float* pp = (sl == tl2) ? uL : &Pt[tl2 - 1 - sl][0];
        #pragma unroll
        for (int i0 = 0; i0 < 64; i0 += 4) {
          u16x4 ra = *(const u16x4*)(rp + i0);
          u16x4 ka = *(const u16x4*)(kp + i0);
          f32x4 pa = *(const f32x4*)(pp + i0);
          #pragma unroll
          for (int di = 0; di < 4; di++)
            a = fmaf(bf2f(ra[di]) * bf2f(ka[di]), pa[di], a);
        }
      }
      aB[(w * 16 + tl2) * 72 + w * 16 + sl] = f2bf(a);
    }
  }
  __syncthreads();

  u16* Ktt = KhX;
  {
    const int ii = tid & 63, s0 = (tid >> 6) * 16;
    #pragma unroll
    for (int ds = 0; ds < 16; ds += 2) {
      float v0 = bf2f(kB[(s0 + ds) * 72 + ii]) * Pt[63 - (s0 + ds)][ii];
      float v1 = bf2f(kB[(s0 + ds + 1) * 72 + ii]) * Pt[63 - (s0 + ds + 1)][ii];
      u32 pk = ((u32)f2bf(v1) << 16) | f2bf(v0);
      *(u32*)&Ktt[ii * 72 + s0 + ds] = pk;
    }
  }
  __syncthreads();

  const int lr = lane & 15, kq = lane >> 4;
  {
    f32x4 yac[4] = {};
    #pragma unroll
    for (int kf2 = 0; kf2 < 2; kf2++) {
      bf16x8 af = *(const bf16x8*)&aB[(w * 16 + lr) * 72 + kf2 * 32 + kq * 8];
      #pragma unroll
      for (int nf = 0; nf < 4; nf++) {
        bf16x8 bf_ = *(const bf16x8*)&Vt[(nf * 16 + lr) * 72 + kf2 * 32 + kq * 8];
        yac[nf] = __builtin_amdgcn_mfma_f32_16x16x32_bf16(af, bf_, yac[nf], 0, 0, 0);
      }
    }
    float* Yp = Yb + (size_t)bid * 4096;
    #pragma unroll
    for (int nf = 0; nf < 4; nf++)
      #pragma unroll
      for (int reg = 0; reg < 4; reg++)
        Yp[(w * 16 + kq * 4 + reg) * 64 + nf * 16 + lr] = yac[nf][reg];

    f32x4 dac[4] = {};
    #pragma unroll
    for (int kf2 = 0; kf2 < 2; kf2++) {
      bf16x8 af = *(const bf16x8*)&Ktt[(w * 16 + lr) * 72 + kf2 * 32 + kq * 8];
      #pragma unroll
      for (int nf = 0; nf < 4; nf++) {
        bf16x8 bf_ = *(const bf16x8*)&Vt[(nf * 16 + lr) * 72 + kf2 * 32 + kq * 8];
        dac[nf] = __builtin_amdgcn_mfma_f32_16x16x32_bf16(af, bf_, dac[nf], 0, 0, 0);
      }
    }
    float* Dp = Db + (size_t)bid * 4096;
    #pragma unroll
    for (int nf = 0; nf < 4; nf++)
      #pragma unroll
      for (int reg = 0; reg < 4; reg++)
        Dp[(w * 16 + kq * 4 + reg) * 64 + nf * 16 + lr] = dac[nf][reg];
  }
}

__global__ __launch_bounds__(256)
void wkv_scan(const float* __restrict__ s0g, const float* __restrict__ td,
              const float* __restrict__ Db, u16* __restrict__ Sbb,
              float* __restrict__ sout) {
  const int bh = blockIdx.x, h = bh & 31;
  const int tid = threadIdx.x;
  const int i = tid >> 2, j0 = (tid & 3) * 16;
  float d = __expf(td[h * 64 + i]);
  float w64 = exp2f(-1.4426950408889634f * d * 64.f);
  f32x4 S[4];
  const float* sp = s0g + ((size_t)bh * 64 + i) * 64 + j0;
  #pragma unroll
  for (int q = 0; q < 4; q++) S[q] = *(const f32x4*)(sp + q * 4);
  for (int c = 0; c < NCH; c++) {
    u16* op = Sbb + ((size_t)(bh * 16 + c)) * 4096 + i * 64 + j0;
    u16x8 o0, o1;
    #pragma unroll
    for (int e = 0; e < 4; e++) { o0[e] = f2bf(S[0][e]); o0[4 + e] = f2bf(S[1][e]);
                                  o1[e] = f2bf(S[2][e]); o1[4 + e] = f2bf(S[3][e]); }
    *(u16x8*)op = o0; *(u16x8*)(op + 8) = o1;
    const float* dp = Db + ((size_t)(bh * 16 + c)) * 4096 + i * 64 + j0;
    #pragma unroll
    for (int q = 0; q < 4; q++) {
      f32x4 dv = *(const f32x4*)(dp + q * 4);
      #pragma unroll
      for (int e = 0; e < 4; e++) S[q][e] = fmaf(w64, S[q][e], dv[e]);
    }
  }
  float* fo = sout + ((size_t)bh * 64 + i) * 64 + j0;
  #pragma unroll
  for (int q = 0; q < 4; q++) *(f32x4*)(fo + q * 4) = S[q];
}

__global__ __launch_bounds__(256)
void wkv_post(const u16* __restrict__ Rtb, const u16* __restrict__ Sbb,
              const float* __restrict__ Yb, const u16* __restrict__ g,
              const float* __restrict__ gnw, const float* __restrict__ gnb,
              u16* __restrict__ xo) {
  __shared__ u16 Rt[64 * 72];
  __shared__ u16 St[64 * 72];
  __shared__ u16 xoL[64 * 72];
  const int tid = threadIdx.x, bid = blockIdx.x;
  const int bh = bid >> 4, c = bid & 15;
  const int b = bh >> 5, h = bh & 31;
  const int lane = tid & 63, w = tid >> 6;
  const int row = tid >> 2, col0 = (tid & 3) * 16;

  {
    const u16* rp = Rtb + (size_t)bid * 4096 + row * 64 + col0;
    u16x8 a0 = *(const u16x8*)rp, a1 = *(const u16x8*)(rp + 8);
    *(u16x8*)&Rt[row * 72 + col0] = a0; *(u16x8*)&Rt[row * 72 + col0 + 8] = a1;
  }
  {
    const u16* sp = Sbb + ((size_t)(bh * 16 + c)) * 4096 + row * 64 + col0;
    u16x8 s0 = *(const u16x8*)sp, s1 = *(const u16x8*)(sp + 8);
    #pragma unroll
    for (int e = 0; e < 8; e++) {
      St[(col0 + e) * 72 + row] = s0[e];
      St[(col0 + 8 + e) * 72 + row] = s1[e];
    }
  }
  const int lr = lane & 15, kq = lane >> 4;
  f32x4 acc[4];
  {
    const float* Yp = Yb + (size_t)bid * 4096;
    #pragma unroll
    for (int nf = 0; nf < 4; nf++)
      #pragma unroll
      for (int reg = 0; reg < 4; reg++)
        acc[nf][reg] = Yp[(w * 16 + kq * 4 + reg) * 64 + nf * 16 + lr];
  }
  __syncthreads();
  #pragma unroll
  for (int kf2 = 0; kf2 < 2; kf2++) {
    bf16x8 af = *(const bf16x8*)&Rt[(w * 16 + lr) * 72 + kf2 * 32 + kq * 8];
    #pragma unroll
    for (int nf = 0; nf < 4; nf++) {
      bf16x8 bf_ = *(const bf16x8*)&St[(nf * 16 + lr) * 72 + kf2 * 32 + kq * 8];
      acc[nf] = __builtin_amdgcn_mfma_f32_16x16x32_bf16(af, bf_, acc[nf], 0, 0, 0);
    }
  }
  #pragma unroll
  for (int reg = 0; reg < 4; reg++) {
    float s = 0.f, ss = 0.f;
    #pragma unroll
    for (int nf = 0; nf < 4; nf++) {
      float z = acc[nf][reg] * 0.125f;
      s += z; ss += z * z;
    }
    #pragma unroll
    for (int m = 1; m < 16; m <<= 1) { s += __shfl_xor(s, m); ss += __shfl_xor(ss, m); }
    float mean = s * (1.f / 64.f);
    float var = ss * (1.f / 64.f) - mean * mean;
    float inv = rsqrtf(var + 1e-5f);
    const int tau = w * 16 + kq * 4 + reg;
    #pragma unroll
    for (int nf = 0; nf < 4; nf++) {
      const int col = nf * 16 + lr;
      float z = acc[nf][reg] * 0.125f;
      float zn = (z - mean) * inv * gnw[h * 64 + col] + gnb[h * 64 + col];
      float gv = bf2f(g[((size_t)b * Tt + c * 64 + tau) * Cc + h * 64 + col]);
      xoL[tau * 72 + col] = f2bf(zn * gv);
    }
  }
  __syncthreads();
  {
    u16x8 o0 = *(const u16x8*)&xoL[row * 72 + col0];
    u16x8 o1 = *(const u16x8*)&xoL[row * 72 + col0 + 8];
    u16* xop = xo + ((size_t)b * Tt + c * 64 + row) * Cc + h * 64 + col0;
    *(u16x8*)xop = o0; *(u16x8*)(xop + 8) = o1;
  }
}

// ---------- orchestration ----------
extern "C" void kernel_launch(void* const* d_in, const int* in_sizes, int n_in,
                              void* d_out, int out_size, void* d_ws, size_t ws_size,
                              hipStream_t stream) {
  const float* x         = (const float*)d_in[0];
  const float* att_shift = (const float*)d_in[1];
  const float* wkv0      = (const float*)d_in[2];
  const float* ffn_shift = (const float*)d_in[3];
  const float* ln1w = (const float*)d_in[4];
  const float* ln1b = (const float*)d_in[5];
  const float* ln2w = (const float*)d_in[6];
  const float* ln2b = (const float*)d_in[7];
  const float* mixk = (const float*)d_in[8];
  const float* mixv = (const float*)d_in[9];
  const float* mixr = (const float*)d_in[10];
  const float* mixg = (const float*)d_in[11];
  const float* Wr = (const float*)d_in[12];
  const float* Wk = (const float*)d_in[13];
  const float* Wv = (const float*)d_in[14];
  const float* Wg = (const float*)d_in[15];
  const float* Wo = (const float*)d_in[16];
  const float* td = (const float*)d_in[17];
  const float* tf = (const float*)d_in[18];
  const float* gnw = (const float*)d_in[19];
  const float* gnb = (const float*)d_in[20];
  const float* cmk = (const float*)d_in[21];
  const float* cmr = (const float*)d_in[22];
  const float* Wck = (const float*)d_in[23];
  const float* Wcr = (const float*)d_in[24];
  const float* Wcv = (const float*)d_in[25];

  constexpr size_t SZ_CC = (size_t)Cc * Cc * 2;
  constexpr size_t SZ_CF = (size_t)Cc * FF * 2;
  constexpr size_t SZ_AB = (size_t)BT * Cc * 2;
  constexpr size_t O_W   = 0;
  constexpr size_t O_R1  = 6 * SZ_CC + 2 * SZ_CF;
  constexpr size_t R1_SZ = 4 * SZ_AB;
  constexpr size_t O_R2  = O_R1 + R1_SZ;
  constexpr size_t R2_SZ = 3 * SZ_AB;
  constexpr size_t O_R3  = O_R2 + R2_SZ;
  constexpr size_t WS_NEED = O_R3 + SZ_AB;

  if (ws_size < WS_NEED) return;

  char* ws = (char*)d_ws;
  u16* WrT  = (u16*)(ws + O_W);
  u16* WkT  = (u16*)(ws + O_W + 1 * SZ_CC);
  u16* WvT  = (u16*)(ws + O_W + 2 * SZ_CC);
  u16* WgT  = (u16*)(ws + O_W + 3 * SZ_CC);
  u16* WoT  = (u16*)(ws + O_W + 4 * SZ_CC);
  u16* WcrT = (u16*)(ws + O_W + 5 * SZ_CC);
  u16* WckT = (u16*)(ws + O_W + 6 * SZ_CC);
  u16* WcvT = (u16*)(ws + O_W + 6 * SZ_CC + SZ_CF);

  u16*   xk  = (u16*)(ws + O_R1);
  u16*   xv  = (u16*)(ws + O_R1 + SZ_AB);
  u16*   xr  = (u16*)(ws + O_R1 + 2 * SZ_AB);
  u16*   xg  = (u16*)(ws + O_R1 + 3 * SZ_AB);
  float* Yb  = (float*)(ws + O_R1);
  u16*   Rtb = (u16*)(ws + O_R1 + 2 * SZ_AB);
  u16*   Sbb = (u16*)(ws + O_R1 + 3 * SZ_AB);
  u16*   kk  = (u16*)(ws + O_R1);
  u16*   rb  = (u16*)(ws + O_R2);
  u16*   kb  = (u16*)(ws + O_R2 + SZ_AB);
  u16*   vb  = (u16*)(ws + O_R2 + 2 * SZ_AB);
  u16*   xcr = (u16*)(ws + O_R2);
  u16*   xck = (u16*)(ws + O_R2 + SZ_AB);
  u16*   xo  = (u16*)(ws + O_R2 + 2 * SZ_AB);
  float* kv0 = (float*)(ws + O_R2 + SZ_AB);
  u16*   gbuf = (u16*)(ws + O_R3);
  u16*   kv1  = (u16*)(ws + O_R3);

  float* out      = (float*)d_out;
  float* x1_last  = out + (size_t)BT * Cc;
  float* wkv_out  = x1_last + (size_t)Bb * Cc;
  float* x2_last  = wkv_out + (size_t)Bb * Hh * Nd * Nd;
  float* Db       = out;  // free until Wo-gemm; scan consumes it first

  transp64_6cc<<<dim3(32, 32, 6), 256, 0, stream>>>(Wr, Wk, Wv, Wg, Wo, Wcr,
                                                    WrT, WkT, WvT, WgT, WoT, WcrT);
  transp64<<<dim3(112, 32), 256, 0, stream>>>(Wck, WckT, Cc, FF);
  transp64<<<dim3(32, 112), 256, 0, stream>>>(Wcv, WcvT, FF, Cc);

  ln_mix4<<<BT, 256, 0, stream>>>(x, att_shift, ln1w, ln1b,
                                  mixk, mixv, mixr, mixg, xk, xv, xr, xg, x1_last);
  gemm256_proj<<<512, 512, 0, stream>>>(xr, xk, xv, xg,
                                        WrT, WkT, WvT, WgT,
                                        rb, kb, vb, gbuf);
  wkv_pre<<<Bb * Hh * NCH, 256, 0, stream>>>(rb, kb, vb, td, tf, Yb, Db, Rtb);
  wkv_scan<<<Bb * Hh, 256, 0, stream>>>(wkv0, td, Db, Sbb, wkv_out);
  wkv_post<<<Bb * Hh * NCH, 256, 0, stream>>>(Rtb, Sbb, Yb, gbuf, gnw, gnb, xo);
  gemm128s<4><<<256, 512, 0, stream>>>(xo, WoT, Cc, Cc, out, nullptr, x,
                                       nullptr, nullptr, 16);
  ln_mix2<<<BT, 256, 0, stream>>>(out, ffn_shift, ln2w, ln2b, cmk, cmr, xck, xcr, x2_last);
  gemm256s<3><<<448, 512, 0, stream>>>(xck, WckT, FF, Cc, nullptr, kk, nullptr, 28);
  gemm256_splitk<<<256, 512, 0, stream>>>(kk, WcvT, kv0, kv1);
  gemm128s<6><<<256, 512, 0, stream>>>(xcr, WcrT, Cc, Cc, out, nullptr, out,
                                       kv0, kv1, 16);

  (void)in_sizes; (void)n_in; (void)out_size;
}

// Round 9
// 726.800 us; speedup vs baseline: 1.0329x; 1.0329x over previous
//
#include <hip/hip_runtime.h>
#include <cstdint>
#include <cstddef>

typedef unsigned short u16;
typedef unsigned int u32;
typedef short bf16x8 __attribute__((ext_vector_type(8)));
typedef unsigned short u16x4 __attribute__((ext_vector_type(4)));
typedef unsigned short u16x8 __attribute__((ext_vector_type(8)));
typedef float f32x4 __attribute__((ext_vector_type(4)));

#define DEV __device__ __forceinline__

// ---------- constants ----------
constexpr int Bb = 4, Tt = 1024, Cc = 2048, Hh = 32, Nd = 64, FF = 7168;
constexpr int BT = Bb * Tt; // 4096
constexpr int NCH = 16;     // chunks of 64

// ---------- helpers ----------
DEV u16 f2bf(float f) {
  union { float f; unsigned u; } un; un.f = f;
  unsigned r = un.u + 0x7FFFu + ((un.u >> 16) & 1u);
  return (u16)(r >> 16);
}
DEV float bf2f(u16 h) {
  union { unsigned u; float f; } un; un.u = ((unsigned)h) << 16;
  return un.f;
}
DEV void gll16(const u16* gp, u16* lp) {
  __builtin_amdgcn_global_load_lds(
      (const __attribute__((address_space(1))) unsigned int*)gp,
      (__attribute__((address_space(3))) unsigned int*)lp,
      16, 0, 0);
}
// XCD-bijective swizzle: each XCD (f%8) owns a contiguous chunk of tile order.
DEV int xcd_swz(int f, int nwg) {
  int q = nwg >> 3;
  return (f & 7) * q + (f >> 3);
}

// ---------- transpose + f32->bf16: W[Kk][Nn] -> Wt[Nn][Kk], 64x64 tiles ----------
DEV void transp64_body(const float* __restrict__ W, u16* __restrict__ Wt,
                       int Kk, int Nn) {
  const int n0 = blockIdx.x * 64, k0 = blockIdx.y * 64;
  const int tx = threadIdx.x & 15, ty = threadIdx.x >> 4;
  const int kk = k0 + ty * 4, nn = n0 + tx * 4;
  const float* p = W + (size_t)kk * Nn + nn;
  f32x4 r0 = *(const f32x4*)(p);
  f32x4 r1 = *(const f32x4*)(p + (size_t)Nn);
  f32x4 r2 = *(const f32x4*)(p + 2 * (size_t)Nn);
  f32x4 r3 = *(const f32x4*)(p + 3 * (size_t)Nn);
  #pragma unroll
  for (int j = 0; j < 4; j++) {
    u16x4 o;
    o[0] = f2bf(r0[j]); o[1] = f2bf(r1[j]); o[2] = f2bf(r2[j]); o[3] = f2bf(r3[j]);
    *(u16x4*)(Wt + (size_t)(nn + j) * Kk + kk) = o;
  }
}

__global__ void transp64(const float* __restrict__ W, u16* __restrict__ Wt,
                         int Kk, int Nn) {
  transp64_body(W, Wt, Kk, Nn);
}

__global__ void transp64_6cc(const float* __restrict__ W0, const float* __restrict__ W1,
                             const float* __restrict__ W2, const float* __restrict__ W3,
                             const float* __restrict__ W4, const float* __restrict__ W5,
                             u16* __restrict__ T0, u16* __restrict__ T1,
                             u16* __restrict__ T2, u16* __restrict__ T3,
                             u16* __restrict__ T4, u16* __restrict__ T5) {
  const int z = blockIdx.z;
  const float* W = (z == 0) ? W0 : (z == 1) ? W1 : (z == 2) ? W2 :
                   (z == 3) ? W3 : (z == 4) ? W4 : W5;
  u16* T = (z == 0) ? T0 : (z == 1) ? T1 : (z == 2) ? T2 :
           (z == 3) ? T3 : (z == 4) ? T4 : T5;
  transp64_body(W, T, Cc, Cc);
}

// ---------- block LayerNorm stats helper ----------
DEV void block_ln(const float* __restrict__ src, int tid, float* red,
                  float vals[8], float& mean, float& inv) {
  float s = 0.f, ss = 0.f;
  #pragma unroll
  for (int i = 0; i < 8; i++) {
    float t = src[tid + i * 256];
    vals[i] = t; s += t; ss += t * t;
  }
  #pragma unroll
  for (int m = 1; m < 64; m <<= 1) { s += __shfl_xor(s, m); ss += __shfl_xor(ss, m); }
  int lane = tid & 63, wv = tid >> 6;
  __syncthreads();
  if (lane == 0) { red[wv] = s; red[4 + wv] = ss; }
  __syncthreads();
  s = red[0] + red[1] + red[2] + red[3];
  ss = red[4] + red[5] + red[6] + red[7];
  mean = s * (1.f / Cc);
  float var = ss * (1.f / Cc) - mean * mean;
  inv = rsqrtf(var + 1e-5f);
}

// ---------- fused LN + 4-way mix ----------
__global__ __launch_bounds__(256)
void ln_mix4(const float* __restrict__ x, const float* __restrict__ shift,
             const float* __restrict__ w, const float* __restrict__ b,
             const float* __restrict__ mk, const float* __restrict__ mv,
             const float* __restrict__ mr, const float* __restrict__ mg,
             u16* __restrict__ xk, u16* __restrict__ xv,
             u16* __restrict__ xr, u16* __restrict__ xg,
             float* __restrict__ last) {
  int row = blockIdx.x;
  int t = row & (Tt - 1), bb = row >> 10;
  int tid = threadIdx.x;
  __shared__ float red[8];
  const float* cur = x + (size_t)row * Cc;
  float cv[8], pv[8], cm, ci, pm = 0.f, pi = 1.f;
  block_ln(cur, tid, red, cv, cm, ci);
  bool t0 = (t == 0);
  const float* prev = t0 ? (shift + (size_t)bb * Cc) : (cur - Cc);
  if (!t0) {
    block_ln(prev, tid, red, pv, pm, pi);
  } else {
    #pragma unroll
    for (int i = 0; i < 8; i++) pv[i] = prev[tid + i * 256];
  }
  size_t o = (size_t)row * Cc;
  bool isLast = (t == Tt - 1);
  #pragma unroll
  for (int i = 0; i < 8; i++) {
    int c = tid + i * 256;
    float xc = (cv[i] - cm) * ci * w[c] + b[c];
    float xp = t0 ? pv[i] : (pv[i] - pm) * pi * w[c] + b[c];
    xk[o + c] = f2bf(xp + mk[c] * (xc - xp));
    xv[o + c] = f2bf(xp + mv[c] * (xc - xp));
    xr[o + c] = f2bf(xp + mr[c] * (xc - xp));
    xg[o + c] = f2bf(xp + mg[c] * (xc - xp));
    if (isLast) last[(size_t)bb * Cc + c] = xc;
  }
}

// ---------- fused LN + 2-way mix ----------
__global__ __launch_bounds__(256)
void ln_mix2(const float* __restrict__ x, const float* __restrict__ shift,
             const float* __restrict__ w, const float* __restrict__ b,
             const float* __restrict__ ck, const float* __restrict__ cr,
             u16* __restrict__ xck, u16* __restrict__ xcr,
             float* __restrict__ last) {
  int row = blockIdx.x;
  int t = row & (Tt - 1), bb = row >> 10;
  int tid = threadIdx.x;
  __shared__ float red[8];
  const float* cur = x + (size_t)row * Cc;
  float cv[8], pv[8], cm, ci, pm = 0.f, pi = 1.f;
  block_ln(cur, tid, red, cv, cm, ci);
  bool t0 = (t == 0);
  const float* prev = t0 ? (shift + (size_t)bb * Cc) : (cur - Cc);
  if (!t0) {
    block_ln(prev, tid, red, pv, pm, pi);
  } else {
    #pragma unroll
    for (int i = 0; i < 8; i++) pv[i] = prev[tid + i * 256];
  }
  size_t o = (size_t)row * Cc;
  bool isLast = (t == Tt - 1);
  #pragma unroll
  for (int i = 0; i < 8; i++) {
    int c = tid + i * 256;
    float xc = (cv[i] - cm) * ci * w[c] + b[c];
    float xp = t0 ? pv[i] : (pv[i] - pm) * pi * w[c] + b[c];
    xck[o + c] = f2bf(xp + ck[c] * (xc - xp));
    xcr[o + c] = f2bf(xp + cr[c] * (xc - xp));
    if (isLast) last[(size_t)bb * Cc + c] = xc;
  }
}

// ====== 256xBN deep-pipelined GEMM (8-wave, BK=64, 16x16x32 MFMA) ======
// 4 phases/K-tile; phase p computes acc columns [p*NB, p*NB+NB) over both
// K-halves (acc-DISJOINT across phases -> MFMA issue never waits on prior
// phase's MFMA completion; matrix-pipe backlog drains through read segments).
// A-frags (both kh) read once at phase 0 and register-cached.
// Staging: B(t+1)h0 @p0, B(t+1)h1 @p1 (NB=2), A(t+2)h0 @p2, A(t+2)h1 @p3;
// vmcnt(4) at p3 (counted; 0 only in tail).
DEV int swzoff(int row, int off) {
  return (row << 7) +
         (off ^ ((((row >> 1) & 1) << 4) | (((row >> 2) & 1) << 5) | (((row >> 3) & 1) << 6)));
}

DEV void stage_half(const u16* __restrict__ gbase, int ldK, u16* slot, int tid) {
  #pragma unroll
  for (int c2 = 0; c2 < 2; c2++) {
    const int D = c2 * 8192 + tid * 16;
    const int row = D >> 7;
    const int off = (D & 127) ^ ((((row >> 1) & 1) << 4) | (((row >> 2) & 1) << 5) | (((row >> 3) & 1) << 6));
    gll16(gbase + (size_t)row * ldK + (off >> 1), (u16*)((char*)slot + D));
  }
}

// EPI: 0=f32, 1=bf16(+act silu), 3=relu^2->bf16, 4=X1+val->f32,
//      6=X1+sigmoid(val)*(X2+bf2f(X2b))->f32
template <int EPI, int NB>
DEV void g256_core(const u16* __restrict__ A, const u16* __restrict__ Bt,
                   int N, int K, int ldK,
                   float* __restrict__ Co, u16* __restrict__ Cb,
                   const float* __restrict__ X1, const float* __restrict__ X2,
                   const u16* __restrict__ X2b,
                   u16 (*lds)[8192], int m0, int n0, int act) {
  const int tid = threadIdx.x;
  const int w = tid >> 6, lane = tid & 63;
  const int l15 = lane & 15, l4 = lane >> 4;
  const int wm = (w & 3) * 64;
  const int wn = (w >> 2) * (NB * 64);
  const int ahalf = wm >> 7;
  const int arow0 = wm & 127;
  const int bhalf = (NB == 2) ? (w >> 2) : 0;
  const int nt = K >> 6;

  const u16* Ag = A + (size_t)m0 * ldK;
  const u16* Bg = Bt + (size_t)n0 * ldK;

  f32x4 acc[4][NB * 4] = {};
  bf16x8 a[4][2];

  stage_half(Ag, ldK, lds[0], tid);
  stage_half(Ag + (size_t)128 * ldK, ldK, lds[1], tid);
  stage_half(Bg, ldK, lds[4], tid);
  if constexpr (NB == 2) stage_half(Bg + (size_t)128 * ldK, ldK, lds[5], tid);
  if (nt > 1) {
    stage_half(Ag + 64, ldK, lds[2], tid);
    stage_half(Ag + (size_t)128 * ldK + 64, ldK, lds[3], tid);
    asm volatile("s_waitcnt vmcnt(4)" ::: "memory");
  } else {
    asm volatile("s_waitcnt vmcnt(0)" ::: "memory");
  }
  asm volatile("s_barrier" ::: "memory");

  for (int t = 0; t < nt; t++) {
    const int buf = t & 1;
    const char* Aslot = (const char*)lds[buf * 2 + ahalf];
    const char* Bslot = (const char*)lds[4 + buf * NB + bhalf];

#define G256_PHASE(p)                                                                       \
    {                                                                                       \
      if constexpr ((p) == 0) {                                                             \
        _Pragma("unroll")                                                                   \
        for (int mf = 0; mf < 4; mf++)                                                      \
          _Pragma("unroll")                                                                 \
          for (int kh = 0; kh < 2; kh++)                                                    \
            a[mf][kh] = *(const bf16x8*)(Aslot +                                            \
                swzoff(arow0 + mf * 16 + l15, kh * 64 + l4 * 16));                          \
      }                                                                                     \
      bf16x8 bfr[NB][2];                                                                    \
      _Pragma("unroll")                                                                     \
      for (int d = 0; d < NB; d++) {                                                        \
        const int jg = (p) * NB + d;                                                        \
        _Pragma("unroll")                                                                   \
        for (int kh = 0; kh < 2; kh++)                                                      \
          bfr[d][kh] = *(const bf16x8*)(Bslot +                                             \
              swzoff((NB == 2 ? 0 : wn) + jg * 16 + l15, kh * 64 + l4 * 16));               \
      }                                                                                     \
      if constexpr ((p) == 0) {                                                             \
        if (t + 1 < nt) stage_half(Bg + (size_t)(t + 1) * 64, ldK,                          \
                                   lds[4 + ((t + 1) & 1) * NB], tid);                       \
      } else if constexpr ((p) == 1) {                                                      \
        if constexpr (NB == 2) {                                                            \
          if (t + 1 < nt) stage_half(Bg + (size_t)128 * ldK + (size_t)(t + 1) * 64, ldK,    \
                                     lds[4 + ((t + 1) & 1) * NB + 1], tid);                 \
        }                                                                                   \
      } else if constexpr ((p) == 2) {                                                      \
        if (t + 2 < nt) stage_half(Ag + (size_t)(t + 2) * 64, ldK, lds[buf << 1], tid);     \
      } else {                                                                              \
        if (t + 2 < nt) stage_half(Ag + (size_t)128 * ldK + (size_t)(t + 2) * 64, ldK,      \
                                   lds[(buf << 1) + 1], tid);                               \
      }                                                                                     \
      asm volatile("s_barrier" ::: "memory");                                               \
      __builtin_amdgcn_s_setprio(1);                                                       \
      _Pragma("unroll")                                                                     \
      for (int mf = 0; mf < 4; mf++)                                                        \
        _Pragma("unroll")                                                                   \
        for (int d = 0; d < NB; d++)                                                        \
          _Pragma("unroll")                                                                 \
          for (int kh = 0; kh < 2; kh++)                                                    \
            acc[mf][(p) * NB + d] = __builtin_amdgcn_mfma_f32_16x16x32_bf16(                \
                a[mf][kh], bfr[d][kh], acc[mf][(p) * NB + d], 0, 0, 0);                     \
      __builtin_amdgcn_s_setprio(0);                                                       \
      if constexpr ((p) == 3) {                                                             \
        if (t + 2 < nt) asm volatile("s_waitcnt vmcnt(4)" ::: "memory");                    \
        else            asm volatile("s_waitcnt vmcnt(0)" ::: "memory");                    \
      }                                                                                     \
      asm volatile("s_barrier" ::: "memory");                                               \
    }

    G256_PHASE(0)
    G256_PHASE(1)
    G256_PHASE(2)
    G256_PHASE(3)
#undef G256_PHASE
  }

  // ---- epilogue ----
  #pragma unroll
  for (int mf = 0; mf < 4; mf++) {
    #pragma unroll
    for (int reg = 0; reg < 4; reg++) {
      const int gr = m0 + wm + mf * 16 + l4 * 4 + reg;
      const size_t ro = (size_t)gr * N;
      #pragma unroll
      for (int nf = 0; nf < NB * 4; nf++) {
        const int gc = n0 + wn + nf * 16 + l15;
        float val = acc[mf][nf][reg];
        if constexpr (EPI == 0) {
          Co[ro + gc] = val;
        } else if constexpr (EPI == 1) {
          if (act) val = val / (1.f + __expf(-val));
          Cb[ro + gc] = f2bf(val);
        } else if constexpr (EPI == 3) {
          float tr = fmaxf(val, 0.f);
          Cb[ro + gc] = f2bf(tr * tr);
        } else if constexpr (EPI == 4) {
          Co[ro + gc] = X1[ro + gc] + val;
        } else {
          float s = 1.f / (1.f + __expf(-val));
          float kvv = X2[ro + gc] + bf2f(X2b[ro + gc]);
          Co[ro + gc] = fmaf(s, kvv, X1[ro + gc]);
        }
      }
    }
  }
}

// BN=256 swizzled wrapper (grid 1D, nwg%8==0; tile order: x fastest over NX)
template <int EPI>
__global__ __launch_bounds__(512)
void gemm256s(const u16* __restrict__ A, const u16* __restrict__ Bt,
              int N, int K,
              float* __restrict__ Co, u16* __restrict__ Cb,
              const float* __restrict__ X1, int NX) {
  __shared__ __align__(16) u16 lds[8][8192];
  int o = xcd_swz(blockIdx.x, gridDim.x);
  int xb = o % NX, yb = o / NX;
  g256_core<EPI, 2>(A, Bt, N, K, K, Co, Cb, X1, nullptr, nullptr, lds,
                    yb * 256, xb * 256, 0);
}

// BN=128 swizzled wrapper
template <int EPI>
__global__ __launch_bounds__(512)
void gemm128s(const u16* __restrict__ A, const u16* __restrict__ Bt,
              int N, int K,
              float* __restrict__ Co, u16* __restrict__ Cb,
              const float* __restrict__ X1, const float* __restrict__ X2,
              const u16* __restrict__ X2b, int NX) {
  __shared__ __align__(16) u16 lds[6][8192];
  int o = xcd_swz(blockIdx.x, gridDim.x);
  int xb = o % NX, yb = o / NX;
  g256_core<EPI, 1>(A, Bt, N, K, K, Co, Cb, X1, X2, X2b, lds,
                    yb * 256, xb * 128, 0);
}

// projection GEMMs: grid 1D = 8*16*4, swizzled
__global__ __launch_bounds__(512)
void gemm256_proj(const u16* __restrict__ A0, const u16* __restrict__ A1,
                  const u16* __restrict__ A2, const u16* __restrict__ A3,
                  const u16* __restrict__ B0, const u16* __restrict__ B1,
                  const u16* __restrict__ B2, const u16* __restrict__ B3,
                  u16* __restrict__ C0, u16* __restrict__ C1,
                  u16* __restrict__ C2, u16* __restrict__ C3) {
  __shared__ __align__(16) u16 lds[8][8192];
  int o = xcd_swz(blockIdx.x, gridDim.x);
  int xb = o & 7, yb = (o >> 3) & 15, z = o >> 7;
  const u16* A = (z == 0) ? A0 : (z == 1) ? A1 : (z == 2) ? A2 : A3;
  const u16* Bt = (z == 0) ? B0 : (z == 1) ? B1 : (z == 2) ? B2 : B3;
  u16* Cb = (z == 0) ? C0 : (z == 1) ? C1 : (z == 2) ? C2 : C3;
  g256_core<1, 2>(A, Bt, Cc, Cc, Cc, nullptr, Cb, nullptr, nullptr, nullptr, lds,
                  yb * 256, xb * 256, z == 3);
}

// split-K=2 Wcv GEMM: z=0 -> f32 partial kv0; z=1 -> bf16 partial kv1.
__global__ __launch_bounds__(512)
void gemm256_splitk(const u16* __restrict__ A, const u16* __restrict__ Bt,
                    float* __restrict__ kv0, u16* __restrict__ kv1) {
  __shared__ __align__(16) u16 lds[8][8192];
  int o = xcd_swz(blockIdx.x, gridDim.x);
  int xb = o & 7, yb = (o >> 3) & 15, z = o >> 7;
  const int Koff = z * (FF / 2);
  if (z == 0)
    g256_core<0, 2>(A + Koff, Bt + Koff, Cc, FF / 2, FF, kv0, nullptr,
                    nullptr, nullptr, nullptr, lds, yb * 256, xb * 256, 0);
  else
    g256_core<1, 2>(A + Koff, Bt + Koff, Cc, FF / 2, FF, nullptr, kv1,
                    nullptr, nullptr, nullptr, lds, yb * 256, xb * 256, 0);
}

// ======================= chunked WKV : three kernels =======================
__global__ __launch_bounds__(256)
void wkv_pre(const u16* __restrict__ rg, const u16* __restrict__ kg,
             const u16* __restrict__ vg, const float* __restrict__ td,
             const float* __restrict__ tf,
             float* __restrict__ Yb, float* __restrict__ Db,
             u16* __restrict__ Rtb) {
  __shared__ float Pt[64][68];
  __shared__ float uL[64];
  __shared__ u16 rB[64 * 72];
  __shared__ u16 kB[64 * 72];
  __shared__ u16 Rh[64 * 72];
  __shared__ u16 KhX[96 * 72];
  __shared__ u16 vA[64 * 72];
  __shared__ u16 Vt[64 * 72];

  const int tid = threadIdx.x, bid = blockIdx.x;
  const int bh = bid >> 4, c = bid & 15;
  const int b = bh >> 5, h = bh & 31;
  const int lane = tid & 63, w = tid >> 6;

  {
    int i = tid & 63;
    float d = __expf(td[h * 64 + i]);
    float c1 = -1.4426950408889634f * d;
    int e0 = (tid >> 6) * 16;
    #pragma unroll
    for (int e = 0; e < 16; e++) Pt[e0 + e][i] = exp2f(c1 * (float)(e0 + e));
    if (tid < 64) uL[tid] = tf[h * 64 + tid];
  }
  __syncthreads();

  const int row = tid >> 2, col0 = (tid & 3) * 16;
  const int tl = row & 15;
  {
    size_t gro = ((size_t)b * Tt + c * 64 + row) * Cc + h * 64 + col0;
    u16x8 rv0 = *(const u16x8*)(rg + gro);
    u16x8 rv1 = *(const u16x8*)(rg + gro + 8);
    u16x8 kv0 = *(const u16x8*)(kg + gro);
    u16x8 kv1 = *(const u16x8*)(kg + gro + 8);
    u16x8 vv0 = *(const u16x8*)(vg + gro);
    u16x8 vv1 = *(const u16x8*)(vg + gro + 8);
    *(u16x8*)&rB[row * 72 + col0] = rv0; *(u16x8*)&rB[row * 72 + col0 + 8] = rv1;
    *(u16x8*)&kB[row * 72 + col0] = kv0; *(u16x8*)&kB[row * 72 + col0 + 8] = kv1;
    *(u16x8*)&vA[row * 72 + col0] = vv0; *(u16x8*)&vA[row * 72 + col0 + 8] = vv1;
    float rf[16], kf[16];
    #pragma unroll
    for (int e = 0; e < 8; e++) { rf[e] = bf2f(rv0[e]); rf[8 + e] = bf2f(rv1[e]); }
    #pragma unroll
    for (int e = 0; e < 8; e++) { kf[e] = bf2f(kv0[e]); kf[8 + e] = bf2f(kv1[e]); }
    u16x8 o0, o1, t0_, t1_;
    #pragma unroll
    for (int e = 0; e < 8; e++) {
      o0[e] = f2bf(rf[e] * Pt[tl][col0 + e]);
      o1[e] = f2bf(rf[8 + e] * Pt[tl][col0 + 8 + e]);
      t0_[e] = f2bf(rf[e] * Pt[row][col0 + e]);
      t1_[e] = f2bf(rf[8 + e] * Pt[row][col0 + 8 + e]);
    }
    *(u16x8*)&Rh[row * 72 + col0] = o0; *(u16x8*)&Rh[row * 72 + col0 + 8] = o1;
    u16* rtp = Rtb + (size_t)bid * 4096 + row * 64 + col0;
    *(u16x8*)rtp = t0_; *(u16x8*)(rtp + 8) = t1_;
    if (row < 48) {
      u16x8 a0, a1;
      #pragma unroll
      for (int e = 0; e < 8; e++) {
        a0[e] = f2bf(kf[e] * Pt[15 - tl][col0 + e]);
        a1[e] = f2bf(kf[8 + e] * Pt[15 - tl][col0 + 8 + e]);
      }
      *(u16x8*)&KhX[row * 72 + col0] = a0; *(u16x8*)&KhX[row * 72 + col0 + 8] = a1;
    }
    if (row < 32) {
      u16x8 a0, a1;
      #pragma unroll
      for (int e = 0; e < 8; e++) {
        a0[e] = f2bf(kf[e] * Pt[31 - tl][col0 + e]);
        a1[e] = f2bf(kf[8 + e] * Pt[31 - tl][col0 + 8 + e]);
      }
      *(u16x8*)&KhX[(48 + row) * 72 + col0] = a0; *(u16x8*)&KhX[(48 + row) * 72 + col0 + 8] = a1;
    }
    if (row < 16) {
      u16x8 a0, a1;
      #pragma unroll
      for (int e = 0; e < 8; e++) {
        a0[e] = f2bf(kf[e] * Pt[47 - tl][col0 + e]);
        a1[e] = f2bf(kf[8 + e] * Pt[47 - tl][col0 + 8 + e]);
      }
      *(u16x8*)&KhX[(80 + row) * 72 + col0] = a0; *(u16x8*)&KhX[(80 + row) * 72 + col0 + 8] = a1;
    }
  }
  __syncthreads();

  {
    const int jj = tid & 63, s0 = (tid >> 6) * 16;
    #pragma unroll
    for (int ds = 0; ds < 16; ds += 2) {
      u32 pk = ((u32)vA[(s0 + ds + 1) * 72 + jj] << 16) | vA[(s0 + ds) * 72 + jj];
      *(u32*)&Vt[jj * 72 + s0 + ds] = pk;
    }
  }
  __syncthreads();

  u16* aB = vA;
  {
    const int pr[6] = {1, 2, 3, 2, 3, 3};
    const int qr[6] = {0, 1, 2, 0, 1, 0};
    const int dr[6] = {0, 0, 0, 1, 1, 2};
    const int lr = lane & 15, kq = lane >> 4;
    for (int pi = w; pi < 6; pi += 4) {
      const int p = pr[pi], q = qr[pi], d = dr[pi];
      const int kbase = (d == 0) ? q * 16 : (d == 1) ? 48 + q * 16 : 80 + q * 16;
      f32x4 aacc = {};
      #pragma unroll
      for (int kf2 = 0; kf2 < 2; kf2++) {
        bf16x8 af = *(const bf16x8*)&Rh[(p * 16 + lr) * 72 + kf2 * 32 + kq * 8];
        bf16x8 bf_ = *(const bf16x8*)&KhX[(kbase + lr) * 72 + kf2 * 32 + kq * 8];
        aacc = __builtin_amdgcn_mfma_f32_16x16x32_bf16(af, bf_, aacc, 0, 0, 0);
      }
      #pragma unroll
      for (int reg = 0; reg < 4; reg++) {
        aB[(p * 16 + kq * 4 + reg) * 72 + q * 16 + lr] = f2bf(aacc[reg]);
        aB[(q * 16 + kq * 4 + reg) * 72 + p * 16 + lr] = 0;
      }
    }
    for (int e = lane; e < 256; e += 64) {
      const int tl2 = e >> 4, sl = e & 15;
      float a = 0.f;
      if (sl <= tl2) {
        const u16* rp = &rB[(w * 16 + tl2) * 72];
        const u16* kp = &kB[(w * 16 + sl) * 72];
        const float* pp = (sl == tl2) ? uL : &Pt[tl2 - 1 - sl][0];
        #pragma unroll
        for (int i0 = 0; i0 < 64; i0 += 4) {
          u16x4 ra = *(const u16x4*)(rp + i0);
          u16x4 ka = *(const u16x4*)(kp + i0);
          f32x4 pa = *(const f32x4*)(pp + i0);
          #pragma unroll
          for (int di = 0; di < 4; di++)
            a = fmaf(bf2f(ra[di]) * bf2f(ka[di]), pa[di], a);
        }
      }
      aB[(w * 16 + tl2) * 72 + w * 16 + sl] = f2bf(a);
    }
  }
  __syncthreads();

  u16* Ktt = KhX;
  {
    const int ii = tid & 63, s0 = (tid >> 6) * 16;
    #pragma unroll
    for (int ds = 0; ds < 16; ds += 2) {
      float v0 = bf2f(kB[(s0 + ds) * 72 + ii]) * Pt[63 - (s0 + ds)][ii];
      float v1 = bf2f(kB[(s0 + ds + 1) * 72 + ii]) * Pt[63 - (s0 + ds + 1)][ii];
      u32 pk = ((u32)f2bf(v1) << 16) | f2bf(v0);
      *(u32*)&Ktt[ii * 72 + s0 + ds] = pk;
    }
  }
  __syncthreads();

  const int lr = lane & 15, kq = lane >> 4;
  {
    f32x4 yac[4] = {};
    #pragma unroll
    for (int kf2 = 0; kf2 < 2; kf2++) {
      bf16x8 af = *(const bf16x8*)&aB[(w * 16 + lr) * 72 + kf2 * 32 + kq * 8];
      #pragma unroll
      for (int nf = 0; nf < 4; nf++) {
        bf16x8 bf_ = *(const bf16x8*)&Vt[(nf * 16 + lr) * 72 + kf2 * 32 + kq * 8];
        yac[nf] = __builtin_amdgcn_mfma_f32_16x16x32_bf16(af, bf_, yac[nf], 0, 0, 0);
      }
    }
    float* Yp = Yb + (size_t)bid * 4096;
    #pragma unroll
    for (int nf = 0; nf < 4; nf++)
      #pragma unroll
      for (int reg = 0; reg < 4; reg++)
        Yp[(w * 16 + kq * 4 + reg) * 64 + nf * 16 + lr] = yac[nf][reg];

    f32x4 dac[4] = {};
    #pragma unroll
    for (int kf2 = 0; kf2 < 2; kf2++) {
      bf16x8 af = *(const bf16x8*)&Ktt[(w * 16 + lr) * 72 + kf2 * 32 + kq * 8];
      #pragma unroll
      for (int nf = 0; nf < 4; nf++) {
        bf16x8 bf_ = *(const bf16x8*)&Vt[(nf * 16 + lr) * 72 + kf2 * 32 + kq * 8];
        dac[nf] = __builtin_amdgcn_mfma_f32_16x16x32_bf16(af, bf_, dac[nf], 0, 0, 0);
      }
    }
    float* Dp = Db + (size_t)bid * 4096;
    #pragma unroll
    for (int nf = 0; nf < 4; nf++)
      #pragma unroll
      for (int reg = 0; reg < 4; reg++)
        Dp[(w * 16 + kq * 4 + reg) * 64 + nf * 16 + lr] = dac[nf][reg];
  }
}

__global__ __launch_bounds__(256)
void wkv_scan(const float* __restrict__ s0g, const float* __restrict__ td,
              const float* __restrict__ Db, u16* __restrict__ Sbb,
              float* __restrict__ sout) {
  const int bh = blockIdx.x, h = bh & 31;
  const int tid = threadIdx.x;
  const int i = tid >> 2, j0 = (tid & 3) * 16;
  float d = __expf(td[h * 64 + i]);
  float w64 = exp2f(-1.4426950408889634f * d * 64.f);
  f32x4 S[4];
  const float* sp = s0g + ((size_t)bh * 64 + i) * 64 + j0;
  #pragma unroll
  for (int q = 0; q < 4; q++) S[q] = *(const f32x4*)(sp + q * 4);
  for (int c = 0; c < NCH; c++) {
    u16* op = Sbb + ((size_t)(bh * 16 + c)) * 4096 + i * 64 + j0;
    u16x8 o0, o1;
    #pragma unroll
    for (int e = 0; e < 4; e++) { o0[e] = f2bf(S[0][e]); o0[4 + e] = f2bf(S[1][e]);
                                  o1[e] = f2bf(S[2][e]); o1[4 + e] = f2bf(S[3][e]); }
    *(u16x8*)op = o0; *(u16x8*)(op + 8) = o1;
    const float* dp = Db + ((size_t)(bh * 16 + c)) * 4096 + i * 64 + j0;
    #pragma unroll
    for (int q = 0; q < 4; q++) {
      f32x4 dv = *(const f32x4*)(dp + q * 4);
      #pragma unroll
      for (int e = 0; e < 4; e++) S[q][e] = fmaf(w64, S[q][e], dv[e]);
    }
  }
  float* fo = sout + ((size_t)bh * 64 + i) * 64 + j0;
  #pragma unroll
  for (int q = 0; q < 4; q++) *(f32x4*)(fo + q * 4) = S[q];
}

__global__ __launch_bounds__(256)
void wkv_post(const u16* __restrict__ Rtb, const u16* __restrict__ Sbb,
              const float* __restrict__ Yb, const u16* __restrict__ g,
              const float* __restrict__ gnw, const float* __restrict__ gnb,
              u16* __restrict__ xo) {
  __shared__ u16 Rt[64 * 72];
  __shared__ u16 St[64 * 72];
  __shared__ u16 xoL[64 * 72];
  const int tid = threadIdx.x, bid = blockIdx.x;
  const int bh = bid >> 4, c = bid & 15;
  const int b = bh >> 5, h = bh & 31;
  const int lane = tid & 63, w = tid >> 6;
  const int row = tid >> 2, col0 = (tid & 3) * 16;

  {
    const u16* rp = Rtb + (size_t)bid * 4096 + row * 64 + col0;
    u16x8 a0 = *(const u16x8*)rp, a1 = *(const u16x8*)(rp + 8);
    *(u16x8*)&Rt[row * 72 + col0] = a0; *(u16x8*)&Rt[row * 72 + col0 + 8] = a1;
  }
  {
    const u16* sp = Sbb + ((size_t)(bh * 16 + c)) * 4096 + row * 64 + col0;
    u16x8 s0 = *(const u16x8*)sp, s1 = *(const u16x8*)(sp + 8);
    #pragma unroll
    for (int e = 0; e < 8; e++) {
      St[(col0 + e) * 72 + row] = s0[e];
      St[(col0 + 8 + e) * 72 + row] = s1[e];
    }
  }
  const int lr = lane & 15, kq = lane >> 4;
  f32x4 acc[4];
  {
    const float* Yp = Yb + (size_t)bid * 4096;
    #pragma unroll
    for (int nf = 0; nf < 4; nf++)
      #pragma unroll
      for (int reg = 0; reg < 4; reg++)
        acc[nf][reg] = Yp[(w * 16 + kq * 4 + reg) * 64 + nf * 16 + lr];
  }
  __syncthreads();
  #pragma unroll
  for (int kf2 = 0; kf2 < 2; kf2++) {
    bf16x8 af = *(const bf16x8*)&Rt[(w * 16 + lr) * 72 + kf2 * 32 + kq * 8];
    #pragma unroll
    for (int nf = 0; nf < 4; nf++) {
      bf16x8 bf_ = *(const bf16x8*)&St[(nf * 16 + lr) * 72 + kf2 * 32 + kq * 8];
      acc[nf] = __builtin_amdgcn_mfma_f32_16x16x32_bf16(af, bf_, acc[nf], 0, 0, 0);
    }
  }
  #pragma unroll
  for (int reg = 0; reg < 4; reg++) {
    float s = 0.f, ss = 0.f;
    #pragma unroll
    for (int nf = 0; nf < 4; nf++) {
      float z = acc[nf][reg] * 0.125f;
      s += z; ss += z * z;
    }
    #pragma unroll
    for (int m = 1; m < 16; m <<= 1) { s += __shfl_xor(s, m); ss += __shfl_xor(ss, m); }
    float mean = s * (1.f / 64.f);
    float var = ss * (1.f / 64.f) - mean * mean;
    float inv = rsqrtf(var + 1e-5f);
    const int tau = w * 16 + kq * 4 + reg;
    #pragma unroll
    for (int nf = 0; nf < 4; nf++) {
      const int col = nf * 16 + lr;
      float z = acc[nf][reg] * 0.125f;
      float zn = (z - mean) * inv * gnw[h * 64 + col] + gnb[h * 64 + col];
      float gv = bf2f(g[((size_t)b * Tt + c * 64 + tau) * Cc + h * 64 + col]);
      xoL[tau * 72 + col] = f2bf(zn * gv);
    }
  }
  __syncthreads();
  {
    u16x8 o0 = *(const u16x8*)&xoL[row * 72 + col0];
    u16x8 o1 = *(const u16x8*)&xoL[row * 72 + col0 + 8];
    u16* xop = xo + ((size_t)b * Tt + c * 64 + row) * Cc + h * 64 + col0;
    *(u16x8*)xop = o0; *(u16x8*)(xop + 8) = o1;
  }
}

// ---------- orchestration ----------
extern "C" void kernel_launch(void* const* d_in, const int* in_sizes, int n_in,
                              void* d_out, int out_size, void* d_ws, size_t ws_size,
                              hipStream_t stream) {
  const float* x         = (const float*)d_in[0];
  const float* att_shift = (const float*)d_in[1];
  const float* wkv0      = (const float*)d_in[2];
  const float* ffn_shift = (const float*)d_in[3];
  const float* ln1w = (const float*)d_in[4];
  const float* ln1b = (const float*)d_in[5];
  const float* ln2w = (const float*)d_in[6];
  const float* ln2b = (const float*)d_in[7];
  const float* mixk = (const float*)d_in[8];
  const float* mixv = (const float*)d_in[9];
  const float* mixr = (const float*)d_in[10];
  const float* mixg = (const float*)d_in[11];
  const float* Wr = (const float*)d_in[12];
  const float* Wk = (const float*)d_in[13];
  const float* Wv = (const float*)d_in[14];
  const float* Wg = (const float*)d_in[15];
  const float* Wo = (const float*)d_in[16];
  const float* td = (const float*)d_in[17];
  const float* tf = (const float*)d_in[18];
  const float* gnw = (const float*)d_in[19];
  const float* gnb = (const float*)d_in[20];
  const float* cmk = (const float*)d_in[21];
  const float* cmr = (const float*)d_in[22];
  const float* Wck = (const float*)d_in[23];
  const float* Wcr = (const float*)d_in[24];
  const float* Wcv = (const float*)d_in[25];

  constexpr size_t SZ_CC = (size_t)Cc * Cc * 2;
  constexpr size_t SZ_CF = (size_t)Cc * FF * 2;
  constexpr size_t SZ_AB = (size_t)BT * Cc * 2;
  constexpr size_t O_W   = 0;
  constexpr size_t O_R1  = 6 * SZ_CC + 2 * SZ_CF;
  constexpr size_t R1_SZ = 4 * SZ_AB;
  constexpr size_t O_R2  = O_R1 + R1_SZ;
  constexpr size_t R2_SZ = 3 * SZ_AB;
  constexpr size_t O_R3  = O_R2 + R2_SZ;
  constexpr size_t WS_NEED = O_R3 + SZ_AB;

  if (ws_size < WS_NEED) return;

  char* ws = (char*)d_ws;
  u16* WrT  = (u16*)(ws + O_W);
  u16* WkT  = (u16*)(ws + O_W + 1 * SZ_CC);
  u16* WvT  = (u16*)(ws + O_W + 2 * SZ_CC);
  u16* WgT  = (u16*)(ws + O_W + 3 * SZ_CC);
  u16* WoT  = (u16*)(ws + O_W + 4 * SZ_CC);
  u16* WcrT = (u16*)(ws + O_W + 5 * SZ_CC);
  u16* WckT = (u16*)(ws + O_W + 6 * SZ_CC);
  u16* WcvT = (u16*)(ws + O_W + 6 * SZ_CC + SZ_CF);

  u16*   xk  = (u16*)(ws + O_R1);
  u16*   xv  = (u16*)(ws + O_R1 + SZ_AB);
  u16*   xr  = (u16*)(ws + O_R1 + 2 * SZ_AB);
  u16*   xg  = (u16*)(ws + O_R1 + 3 * SZ_AB);
  float* Yb  = (float*)(ws + O_R1);
  u16*   Rtb = (u16*)(ws + O_R1 + 2 * SZ_AB);
  u16*   Sbb = (u16*)(ws + O_R1 + 3 * SZ_AB);
  u16*   kk  = (u16*)(ws + O_R1);
  u16*   rb  = (u16*)(ws + O_R2);
  u16*   kb  = (u16*)(ws + O_R2 + SZ_AB);
  u16*   vb  = (u16*)(ws + O_R2 + 2 * SZ_AB);
  u16*   xcr = (u16*)(ws + O_R2);
  u16*   xck = (u16*)(ws + O_R2 + SZ_AB);
  u16*   xo  = (u16*)(ws + O_R2 + 2 * SZ_AB);
  float* kv0 = (float*)(ws + O_R2 + SZ_AB);
  u16*   gbuf = (u16*)(ws + O_R3);
  u16*   kv1  = (u16*)(ws + O_R3);

  float* out      = (float*)d_out;
  float* x1_last  = out + (size_t)BT * Cc;
  float* wkv_out  = x1_last + (size_t)Bb * Cc;
  float* x2_last  = wkv_out + (size_t)Bb * Hh * Nd * Nd;
  float* Db       = out;  // free until Wo-gemm; scan consumes it first

  transp64_6cc<<<dim3(32, 32, 6), 256, 0, stream>>>(Wr, Wk, Wv, Wg, Wo, Wcr,
                                                    WrT, WkT, WvT, WgT, WoT, WcrT);
  transp64<<<dim3(112, 32), 256, 0, stream>>>(Wck, WckT, Cc, FF);
  transp64<<<dim3(32, 112), 256, 0, stream>>>(Wcv, WcvT, FF, Cc);

  ln_mix4<<<BT, 256, 0, stream>>>(x, att_shift, ln1w, ln1b,
                                  mixk, mixv, mixr, mixg, xk, xv, xr, xg, x1_last);
  gemm256_proj<<<512, 512, 0, stream>>>(xr, xk, xv, xg,
                                        WrT, WkT, WvT, WgT,
                                        rb, kb, vb, gbuf);
  wkv_pre<<<Bb * Hh * NCH, 256, 0, stream>>>(rb, kb, vb, td, tf, Yb, Db, Rtb);
  wkv_scan<<<Bb * Hh, 256, 0, stream>>>(wkv0, td, Db, Sbb, wkv_out);
  wkv_post<<<Bb * Hh * NCH, 256, 0, stream>>>(Rtb, Sbb, Yb, gbuf, gnw, gnb, xo);
  gemm128s<4><<<256, 512, 0, stream>>>(xo, WoT, Cc, Cc, out, nullptr, x,
                                       nullptr, nullptr, 16);
  ln_mix2<<<BT, 256, 0, stream>>>(out, ffn_shift, ln2w, ln2b, cmk, cmr, xck, xcr, x2_last);
  gemm256s<3><<<448, 512, 0, stream>>>(xck, WckT, FF, Cc, nullptr, kk, nullptr, 28);
  gemm256_splitk<<<256, 512, 0, stream>>>(kk, WcvT, kv0, kv1);
  gemm128s<6><<<256, 512, 0, stream>>>(xcr, WcrT, Cc, Cc, out, nullptr, out,
                                       kv0, kv1, 16);

  (void)in_sizes; (void)n_in; (void)out_size;
}

// Round 10
// 717.104 us; speedup vs baseline: 1.0469x; 1.0135x over previous
//
#include <hip/hip_runtime.h>
#include <cstdint>
#include <cstddef>

typedef unsigned short u16;
typedef unsigned int u32;
typedef short bf16x8 __attribute__((ext_vector_type(8)));
typedef unsigned short u16x4 __attribute__((ext_vector_type(4)));
typedef unsigned short u16x8 __attribute__((ext_vector_type(8)));
typedef float f32x4 __attribute__((ext_vector_type(4)));

#define DEV __device__ __forceinline__

// ---------- constants ----------
constexpr int Bb = 4, Tt = 1024, Cc = 2048, Hh = 32, Nd = 64, FF = 7168;
constexpr int BT = Bb * Tt; // 4096
constexpr int NCH = 16;     // chunks of 64

// ---------- helpers ----------
DEV u16 f2bf(float f) {
  union { float f; unsigned u; } un; un.f = f;
  unsigned r = un.u + 0x7FFFu + ((un.u >> 16) & 1u);
  return (u16)(r >> 16);
}
DEV float bf2f(u16 h) {
  union { unsigned u; float f; } un; un.u = ((unsigned)h) << 16;
  return un.f;
}
DEV void gll16(const u16* gp, u16* lp) {
  __builtin_amdgcn_global_load_lds(
      (const __attribute__((address_space(1))) unsigned int*)gp,
      (__attribute__((address_space(3))) unsigned int*)lp,
      16, 0, 0);
}
// XCD-bijective swizzle: each XCD (f%8) owns a contiguous chunk of tile order.
DEV int xcd_swz(int f, int nwg) {
  int q = nwg >> 3;
  return (f & 7) * q + (f >> 3);
}

// ---------- transpose + f32->bf16: W[Kk][Nn] -> Wt[Nn][Kk], 64x64 tiles ----------
DEV void transp64_body(const float* __restrict__ W, u16* __restrict__ Wt,
                       int Kk, int Nn) {
  const int n0 = blockIdx.x * 64, k0 = blockIdx.y * 64;
  const int tx = threadIdx.x & 15, ty = threadIdx.x >> 4;
  const int kk = k0 + ty * 4, nn = n0 + tx * 4;
  const float* p = W + (size_t)kk * Nn + nn;
  f32x4 r0 = *(const f32x4*)(p);
  f32x4 r1 = *(const f32x4*)(p + (size_t)Nn);
  f32x4 r2 = *(const f32x4*)(p + 2 * (size_t)Nn);
  f32x4 r3 = *(const f32x4*)(p + 3 * (size_t)Nn);
  #pragma unroll
  for (int j = 0; j < 4; j++) {
    u16x4 o;
    o[0] = f2bf(r0[j]); o[1] = f2bf(r1[j]); o[2] = f2bf(r2[j]); o[3] = f2bf(r3[j]);
    *(u16x4*)(Wt + (size_t)(nn + j) * Kk + kk) = o;
  }
}

__global__ void transp64(const float* __restrict__ W, u16* __restrict__ Wt,
                         int Kk, int Nn) {
  transp64_body(W, Wt, Kk, Nn);
}

__global__ void transp64_6cc(const float* __restrict__ W0, const float* __restrict__ W1,
                             const float* __restrict__ W2, const float* __restrict__ W3,
                             const float* __restrict__ W4, const float* __restrict__ W5,
                             u16* __restrict__ T0, u16* __restrict__ T1,
                             u16* __restrict__ T2, u16* __restrict__ T3,
                             u16* __restrict__ T4, u16* __restrict__ T5) {
  const int z = blockIdx.z;
  const float* W = (z == 0) ? W0 : (z == 1) ? W1 : (z == 2) ? W2 :
                   (z == 3) ? W3 : (z == 4) ? W4 : W5;
  u16* T = (z == 0) ? T0 : (z == 1) ? T1 : (z == 2) ? T2 :
           (z == 3) ? T3 : (z == 4) ? T4 : T5;
  transp64_body(W, T, Cc, Cc);
}

// ---------- block LayerNorm stats helper ----------
DEV void block_ln(const float* __restrict__ src, int tid, float* red,
                  float vals[8], float& mean, float& inv) {
  float s = 0.f, ss = 0.f;
  #pragma unroll
  for (int i = 0; i < 8; i++) {
    float t = src[tid + i * 256];
    vals[i] = t; s += t; ss += t * t;
  }
  #pragma unroll
  for (int m = 1; m < 64; m <<= 1) { s += __shfl_xor(s, m); ss += __shfl_xor(ss, m); }
  int lane = tid & 63, wv = tid >> 6;
  __syncthreads();
  if (lane == 0) { red[wv] = s; red[4 + wv] = ss; }
  __syncthreads();
  s = red[0] + red[1] + red[2] + red[3];
  ss = red[4] + red[5] + red[6] + red[7];
  mean = s * (1.f / Cc);
  float var = ss * (1.f / Cc) - mean * mean;
  inv = rsqrtf(var + 1e-5f);
}

// ---------- fused LN + 4-way mix ----------
__global__ __launch_bounds__(256)
void ln_mix4(const float* __restrict__ x, const float* __restrict__ shift,
             const float* __restrict__ w, const float* __restrict__ b,
             const float* __restrict__ mk, const float* __restrict__ mv,
             const float* __restrict__ mr, const float* __restrict__ mg,
             u16* __restrict__ xk, u16* __restrict__ xv,
             u16* __restrict__ xr, u16* __restrict__ xg,
             float* __restrict__ last) {
  int row = blockIdx.x;
  int t = row & (Tt - 1), bb = row >> 10;
  int tid = threadIdx.x;
  __shared__ float red[8];
  const float* cur = x + (size_t)row * Cc;
  float cv[8], pv[8], cm, ci, pm = 0.f, pi = 1.f;
  block_ln(cur, tid, red, cv, cm, ci);
  bool t0 = (t == 0);
  const float* prev = t0 ? (shift + (size_t)bb * Cc) : (cur - Cc);
  if (!t0) {
    block_ln(prev, tid, red, pv, pm, pi);
  } else {
    #pragma unroll
    for (int i = 0; i < 8; i++) pv[i] = prev[tid + i * 256];
  }
  size_t o = (size_t)row * Cc;
  bool isLast = (t == Tt - 1);
  #pragma unroll
  for (int i = 0; i < 8; i++) {
    int c = tid + i * 256;
    float xc = (cv[i] - cm) * ci * w[c] + b[c];
    float xp = t0 ? pv[i] : (pv[i] - pm) * pi * w[c] + b[c];
    xk[o + c] = f2bf(xp + mk[c] * (xc - xp));
    xv[o + c] = f2bf(xp + mv[c] * (xc - xp));
    xr[o + c] = f2bf(xp + mr[c] * (xc - xp));
    xg[o + c] = f2bf(xp + mg[c] * (xc - xp));
    if (isLast) last[(size_t)bb * Cc + c] = xc;
  }
}

// ---------- fused LN + 2-way mix ----------
__global__ __launch_bounds__(256)
void ln_mix2(const float* __restrict__ x, const float* __restrict__ shift,
             const float* __restrict__ w, const float* __restrict__ b,
             const float* __restrict__ ck, const float* __restrict__ cr,
             u16* __restrict__ xck, u16* __restrict__ xcr,
             float* __restrict__ last) {
  int row = blockIdx.x;
  int t = row & (Tt - 1), bb = row >> 10;
  int tid = threadIdx.x;
  __shared__ float red[8];
  const float* cur = x + (size_t)row * Cc;
  float cv[8], pv[8], cm, ci, pm = 0.f, pi = 1.f;
  block_ln(cur, tid, red, cv, cm, ci);
  bool t0 = (t == 0);
  const float* prev = t0 ? (shift + (size_t)bb * Cc) : (cur - Cc);
  if (!t0) {
    block_ln(prev, tid, red, pv, pm, pi);
  } else {
    #pragma unroll
    for (int i = 0; i < 8; i++) pv[i] = prev[tid + i * 256];
  }
  size_t o = (size_t)row * Cc;
  bool isLast = (t == Tt - 1);
  #pragma unroll
  for (int i = 0; i < 8; i++) {
    int c = tid + i * 256;
    float xc = (cv[i] - cm) * ci * w[c] + b[c];
    float xp = t0 ? pv[i] : (pv[i] - pm) * pi * w[c] + b[c];
    xck[o + c] = f2bf(xp + ck[c] * (xc - xp));
    xcr[o + c] = f2bf(xp + cr[c] * (xc - xp));
    if (isLast) last[(size_t)bb * Cc + c] = xc;
  }
}

// ====== 256xBN deep-pipelined GEMM (8-wave, BK=64, 16x16x32 MFMA) ======
// 4 phases/K-tile, ONE barrier per phase: [ds_reads(p); stage(p); MFMA(p);
// (vmcnt@p3); barrier]. No barrier between reads and MFMA: a wave's reads
// complete (lgkm) before its own MFMA; while one SIMD-mate is blocked issuing
// MFMA, the other issues ds_reads -> MFMA pipe and LDS overlap.
// Safety: stage targets are other-buf B (p0,p1) / current-buf A (p2,p3);
// same-segment reads are current-buf B (A read only @p0, A-writes issue @p2,
// one barrier after all A-reads were consumed) -> disjoint. vmcnt ledger
// identical to the verified 2-barrier version (same issue order/wait point).
DEV int swzoff(int row, int off) {
  return (row << 7) +
         (off ^ ((((row >> 1) & 1) << 4) | (((row >> 2) & 1) << 5) | (((row >> 3) & 1) << 6)));
}

DEV void stage_half(const u16* __restrict__ gbase, int ldK, u16* slot, int tid) {
  #pragma unroll
  for (int c2 = 0; c2 < 2; c2++) {
    const int D = c2 * 8192 + tid * 16;
    const int row = D >> 7;
    const int off = (D & 127) ^ ((((row >> 1) & 1) << 4) | (((row >> 2) & 1) << 5) | (((row >> 3) & 1) << 6));
    gll16(gbase + (size_t)row * ldK + (off >> 1), (u16*)((char*)slot + D));
  }
}

// EPI: 0=f32, 1=bf16(+act silu), 3=relu^2->bf16, 4=X1+val->f32,
//      6=X1+sigmoid(val)*(X2+bf2f(X2b))->f32
template <int EPI, int NB>
DEV void g256_core(const u16* __restrict__ A, const u16* __restrict__ Bt,
                   int N, int K, int ldK,
                   float* __restrict__ Co, u16* __restrict__ Cb,
                   const float* __restrict__ X1, const float* __restrict__ X2,
                   const u16* __restrict__ X2b,
                   u16 (*lds)[8192], int m0, int n0, int act) {
  const int tid = threadIdx.x;
  const int w = tid >> 6, lane = tid & 63;
  const int l15 = lane & 15, l4 = lane >> 4;
  const int wm = (w & 3) * 64;
  const int wn = (w >> 2) * (NB * 64);
  const int ahalf = wm >> 7;
  const int arow0 = wm & 127;
  const int bhalf = (NB == 2) ? (w >> 2) : 0;
  const int nt = K >> 6;

  const u16* Ag = A + (size_t)m0 * ldK;
  const u16* Bg = Bt + (size_t)n0 * ldK;

  f32x4 acc[4][NB * 4] = {};
  bf16x8 a[4][2];

  stage_half(Ag, ldK, lds[0], tid);
  stage_half(Ag + (size_t)128 * ldK, ldK, lds[1], tid);
  stage_half(Bg, ldK, lds[4], tid);
  if constexpr (NB == 2) stage_half(Bg + (size_t)128 * ldK, ldK, lds[5], tid);
  if (nt > 1) {
    stage_half(Ag + 64, ldK, lds[2], tid);
    stage_half(Ag + (size_t)128 * ldK + 64, ldK, lds[3], tid);
    asm volatile("s_waitcnt vmcnt(4)" ::: "memory");
  } else {
    asm volatile("s_waitcnt vmcnt(0)" ::: "memory");
  }
  asm volatile("s_barrier" ::: "memory");

  for (int t = 0; t < nt; t++) {
    const int buf = t & 1;
    const char* Aslot = (const char*)lds[buf * 2 + ahalf];
    const char* Bslot = (const char*)lds[4 + buf * NB + bhalf];

#define G256_PHASE(p)                                                                       \
    {                                                                                       \
      if constexpr ((p) == 0) {                                                             \
        _Pragma("unroll")                                                                   \
        for (int mf = 0; mf < 4; mf++)                                                      \
          _Pragma("unroll")                                                                 \
          for (int kh = 0; kh < 2; kh++)                                                    \
            a[mf][kh] = *(const bf16x8*)(Aslot +                                            \
                swzoff(arow0 + mf * 16 + l15, kh * 64 + l4 * 16));                          \
      }                                                                                     \
      bf16x8 bfr[NB][2];                                                                    \
      _Pragma("unroll")                                                                     \
      for (int d = 0; d < NB; d++) {                                                        \
        const int jg = (p) * NB + d;                                                        \
        _Pragma("unroll")                                                                   \
        for (int kh = 0; kh < 2; kh++)                                                      \
          bfr[d][kh] = *(const bf16x8*)(Bslot +                                             \
              swzoff((NB == 2 ? 0 : wn) + jg * 16 + l15, kh * 64 + l4 * 16));               \
      }                                                                                     \
      if constexpr ((p) == 0) {                                                             \
        if (t + 1 < nt) stage_half(Bg + (size_t)(t + 1) * 64, ldK,                          \
                                   lds[4 + ((t + 1) & 1) * NB], tid);                       \
      } else if constexpr ((p) == 1) {                                                      \
        if constexpr (NB == 2) {                                                            \
          if (t + 1 < nt) stage_half(Bg + (size_t)128 * ldK + (size_t)(t + 1) * 64, ldK,    \
                                     lds[4 + ((t + 1) & 1) * NB + 1], tid);                 \
        }                                                                                   \
      } else if constexpr ((p) == 2) {                                                      \
        if (t + 2 < nt) stage_half(Ag + (size_t)(t + 2) * 64, ldK, lds[buf << 1], tid);     \
      } else {                                                                              \
        if (t + 2 < nt) stage_half(Ag + (size_t)128 * ldK + (size_t)(t + 2) * 64, ldK,      \
                                   lds[(buf << 1) + 1], tid);                               \
      }                                                                                     \
      __builtin_amdgcn_s_setprio(1);                                                       \
      _Pragma("unroll")                                                                     \
      for (int mf = 0; mf < 4; mf++)                                                        \
        _Pragma("unroll")                                                                   \
        for (int d = 0; d < NB; d++)                                                        \
          _Pragma("unroll")                                                                 \
          for (int kh = 0; kh < 2; kh++)                                                    \
            acc[mf][(p) * NB + d] = __builtin_amdgcn_mfma_f32_16x16x32_bf16(                \
                a[mf][kh], bfr[d][kh], acc[mf][(p) * NB + d], 0, 0, 0);                     \
      __builtin_amdgcn_s_setprio(0);                                                       \
      if constexpr ((p) == 3) {                                                             \
        if (t + 2 < nt) asm volatile("s_waitcnt vmcnt(4)" ::: "memory");                    \
        else            asm volatile("s_waitcnt vmcnt(0)" ::: "memory");                    \
      }                                                                                     \
      asm volatile("s_barrier" ::: "memory");                                               \
    }

    G256_PHASE(0)
    G256_PHASE(1)
    G256_PHASE(2)
    G256_PHASE(3)
#undef G256_PHASE
  }

  // ---- epilogue ----
  #pragma unroll
  for (int mf = 0; mf < 4; mf++) {
    #pragma unroll
    for (int reg = 0; reg < 4; reg++) {
      const int gr = m0 + wm + mf * 16 + l4 * 4 + reg;
      const size_t ro = (size_t)gr * N;
      #pragma unroll
      for (int nf = 0; nf < NB * 4; nf++) {
        const int gc = n0 + wn + nf * 16 + l15;
        float val = acc[mf][nf][reg];
        if constexpr (EPI == 0) {
          Co[ro + gc] = val;
        } else if constexpr (EPI == 1) {
          if (act) val = val / (1.f + __expf(-val));
          Cb[ro + gc] = f2bf(val);
        } else if constexpr (EPI == 3) {
          float tr = fmaxf(val, 0.f);
          Cb[ro + gc] = f2bf(tr * tr);
        } else if constexpr (EPI == 4) {
          Co[ro + gc] = X1[ro + gc] + val;
        } else {
          float s = 1.f / (1.f + __expf(-val));
          float kvv = X2[ro + gc] + bf2f(X2b[ro + gc]);
          Co[ro + gc] = fmaf(s, kvv, X1[ro + gc]);
        }
      }
    }
  }
}

// BN=256 swizzled wrapper (grid 1D, nwg%8==0; tile order: x fastest over NX)
template <int EPI>
__global__ __launch_bounds__(512)
void gemm256s(const u16* __restrict__ A, const u16* __restrict__ Bt,
              int N, int K,
              float* __restrict__ Co, u16* __restrict__ Cb,
              const float* __restrict__ X1, int NX) {
  __shared__ __align__(16) u16 lds[8][8192];
  int o = xcd_swz(blockIdx.x, gridDim.x);
  int xb = o % NX, yb = o / NX;
  g256_core<EPI, 2>(A, Bt, N, K, K, Co, Cb, X1, nullptr, nullptr, lds,
                    yb * 256, xb * 256, 0);
}

// BN=128 swizzled wrapper
template <int EPI>
__global__ __launch_bounds__(512)
void gemm128s(const u16* __restrict__ A, const u16* __restrict__ Bt,
              int N, int K,
              float* __restrict__ Co, u16* __restrict__ Cb,
              const float* __restrict__ X1, const float* __restrict__ X2,
              const u16* __restrict__ X2b, int NX) {
  __shared__ __align__(16) u16 lds[6][8192];
  int o = xcd_swz(blockIdx.x, gridDim.x);
  int xb = o % NX, yb = o / NX;
  g256_core<EPI, 1>(A, Bt, N, K, K, Co, Cb, X1, X2, X2b, lds,
                    yb * 256, xb * 128, 0);
}

// projection GEMMs: grid 1D = 8*16*4, swizzled
__global__ __launch_bounds__(512)
void gemm256_proj(const u16* __restrict__ A0, const u16* __restrict__ A1,
                  const u16* __restrict__ A2, const u16* __restrict__ A3,
                  const u16* __restrict__ B0, const u16* __restrict__ B1,
                  const u16* __restrict__ B2, const u16* __restrict__ B3,
                  u16* __restrict__ C0, u16* __restrict__ C1,
                  u16* __restrict__ C2, u16* __restrict__ C3) {
  __shared__ __align__(16) u16 lds[8][8192];
  int o = xcd_swz(blockIdx.x, gridDim.x);
  int xb = o & 7, yb = (o >> 3) & 15, z = o >> 7;
  const u16* A = (z == 0) ? A0 : (z == 1) ? A1 : (z == 2) ? A2 : A3;
  const u16* Bt = (z == 0) ? B0 : (z == 1) ? B1 : (z == 2) ? B2 : B3;
  u16* Cb = (z == 0) ? C0 : (z == 1) ? C1 : (z == 2) ? C2 : C3;
  g256_core<1, 2>(A, Bt, Cc, Cc, Cc, nullptr, Cb, nullptr, nullptr, nullptr, lds,
                  yb * 256, xb * 256, z == 3);
}

// split-K=2 Wcv GEMM: z=0 -> f32 partial kv0; z=1 -> bf16 partial kv1.
__global__ __launch_bounds__(512)
void gemm256_splitk(const u16* __restrict__ A, const u16* __restrict__ Bt,
                    float* __restrict__ kv0, u16* __restrict__ kv1) {
  __shared__ __align__(16) u16 lds[8][8192];
  int o = xcd_swz(blockIdx.x, gridDim.x);
  int xb = o & 7, yb = (o >> 3) & 15, z = o >> 7;
  const int Koff = z * (FF / 2);
  if (z == 0)
    g256_core<0, 2>(A + Koff, Bt + Koff, Cc, FF / 2, FF, kv0, nullptr,
                    nullptr, nullptr, nullptr, lds, yb * 256, xb * 256, 0);
  else
    g256_core<1, 2>(A + Koff, Bt + Koff, Cc, FF / 2, FF, nullptr, kv1,
                    nullptr, nullptr, nullptr, lds, yb * 256, xb * 256, 0);
}

// ======================= chunked WKV : three kernels =======================
__global__ __launch_bounds__(256)
void wkv_pre(const u16* __restrict__ rg, const u16* __restrict__ kg,
             const u16* __restrict__ vg, const float* __restrict__ td,
             const float* __restrict__ tf,
             float* __restrict__ Yb, float* __restrict__ Db,
             u16* __restrict__ Rtb) {
  __shared__ float Pt[64][68];
  __shared__ float uL[64];
  __shared__ u16 rB[64 * 72];
  __shared__ u16 kB[64 * 72];
  __shared__ u16 Rh[64 * 72];
  __shared__ u16 KhX[96 * 72];
  __shared__ u16 vA[64 * 72];
  __shared__ u16 Vt[64 * 72];

  const int tid = threadIdx.x, bid = blockIdx.x;
  const int bh = bid >> 4, c = bid & 15;
  const int b = bh >> 5, h = bh & 31;
  const int lane = tid & 63, w = tid >> 6;

  {
    int i = tid & 63;
    float d = __expf(td[h * 64 + i]);
    float c1 = -1.4426950408889634f * d;
    int e0 = (tid >> 6) * 16;
    #pragma unroll
    for (int e = 0; e < 16; e++) Pt[e0 + e][i] = exp2f(c1 * (float)(e0 + e));
    if (tid < 64) uL[tid] = tf[h * 64 + tid];
  }
  __syncthreads();

  const int row = tid >> 2, col0 = (tid & 3) * 16;
  const int tl = row & 15;
  {
    size_t gro = ((size_t)b * Tt + c * 64 + row) * Cc + h * 64 + col0;
    u16x8 rv0 = *(const u16x8*)(rg + gro);
    u16x8 rv1 = *(const u16x8*)(rg + gro + 8);
    u16x8 kv0 = *(const u16x8*)(kg + gro);
    u16x8 kv1 = *(const u16x8*)(kg + gro + 8);
    u16x8 vv0 = *(const u16x8*)(vg + gro);
    u16x8 vv1 = *(const u16x8*)(vg + gro + 8);
    *(u16x8*)&rB[row * 72 + col0] = rv0; *(u16x8*)&rB[row * 72 + col0 + 8] = rv1;
    *(u16x8*)&kB[row * 72 + col0] = kv0; *(u16x8*)&kB[row * 72 + col0 + 8] = kv1;
    *(u16x8*)&vA[row * 72 + col0] = vv0; *(u16x8*)&vA[row * 72 + col0 + 8] = vv1;
    float rf[16], kf[16];
    #pragma unroll
    for (int e = 0; e < 8; e++) { rf[e] = bf2f(rv0[e]); rf[8 + e] = bf2f(rv1[e]); }
    #pragma unroll
    for (int e = 0; e < 8; e++) { kf[e] = bf2f(kv0[e]); kf[8 + e] = bf2f(kv1[e]); }
    u16x8 o0, o1, t0_, t1_;
    #pragma unroll
    for (int e = 0; e < 8; e++) {
      o0[e] = f2bf(rf[e] * Pt[tl][col0 + e]);
      o1[e] = f2bf(rf[8 + e] * Pt[tl][col0 + 8 + e]);
      t0_[e] = f2bf(rf[e] * Pt[row][col0 + e]);
      t1_[e] = f2bf(rf[8 + e] * Pt[row][col0 + 8 + e]);
    }
    *(u16x8*)&Rh[row * 72 + col0] = o0; *(u16x8*)&Rh[row * 72 + col0 + 8] = o1;
    u16* rtp = Rtb + (size_t)bid * 4096 + row * 64 + col0;
    *(u16x8*)rtp = t0_; *(u16x8*)(rtp + 8) = t1_;
    if (row < 48) {
      u16x8 a0, a1;
      #pragma unroll
      for (int e = 0; e < 8; e++) {
        a0[e] = f2bf(kf[e] * Pt[15 - tl][col0 + e]);
        a1[e] = f2bf(kf[8 + e] * Pt[15 - tl][col0 + 8 + e]);
      }
      *(u16x8*)&KhX[row * 72 + col0] = a0; *(u16x8*)&KhX[row * 72 + col0 + 8] = a1;
    }
    if (row < 32) {
      u16x8 a0, a1;
      #pragma unroll
      for (int e = 0; e < 8; e++) {
        a0[e] = f2bf(kf[e] * Pt[31 - tl][col0 + e]);
        a1[e] = f2bf(kf[8 + e] * Pt[31 - tl][col0 + 8 + e]);
      }
      *(u16x8*)&KhX[(48 + row) * 72 + col0] = a0; *(u16x8*)&KhX[(48 + row) * 72 + col0 + 8] = a1;
    }
    if (row < 16) {
      u16x8 a0, a1;
      #pragma unroll
      for (int e = 0; e < 8; e++) {
        a0[e] = f2bf(kf[e] * Pt[47 - tl][col0 + e]);
        a1[e] = f2bf(kf[8 + e] * Pt[47 - tl][col0 + 8 + e]);
      }
      *(u16x8*)&KhX[(80 + row) * 72 + col0] = a0; *(u16x8*)&KhX[(80 + row) * 72 + col0 + 8] = a1;
    }
  }
  __syncthreads();

  {
    const int jj = tid & 63, s0 = (tid >> 6) * 16;
    #pragma unroll
    for (int ds = 0; ds < 16; ds += 2) {
      u32 pk = ((u32)vA[(s0 + ds + 1) * 72 + jj] << 16) | vA[(s0 + ds) * 72 + jj];
      *(u32*)&Vt[jj * 72 + s0 + ds] = pk;
    }
  }
  __syncthreads();

  u16* aB = vA;
  {
    const int pr[6] = {1, 2, 3, 2, 3, 3};
    const int qr[6] = {0, 1, 2, 0, 1, 0};
    const int dr[6] = {0, 0, 0, 1, 1, 2};
    const int lr = lane & 15, kq = lane >> 4;
    for (int pi = w; pi < 6; pi += 4) {
      const int p = pr[pi], q = qr[pi], d = dr[pi];
      const int kbase = (d == 0) ? q * 16 : (d == 1) ? 48 + q * 16 : 80 + q * 16;
      f32x4 aacc = {};
      #pragma unroll
      for (int kf2 = 0; kf2 < 2; kf2++) {
        bf16x8 af = *(const bf16x8*)&Rh[(p * 16 + lr) * 72 + kf2 * 32 + kq * 8];
        bf16x8 bf_ = *(const bf16x8*)&KhX[(kbase + lr) * 72 + kf2 * 32 + kq * 8];
        aacc = __builtin_amdgcn_mfma_f32_16x16x32_bf16(af, bf_, aacc, 0, 0, 0);
      }
      #pragma unroll
      for (int reg = 0; reg < 4; reg++) {
        aB[(p * 16 + kq * 4 + reg) * 72 + q * 16 + lr] = f2bf(aacc[reg]);
        aB[(q * 16 + kq * 4 + reg) * 72 + p * 16 + lr] = 0;
      }
    }
    for (int e = lane; e < 256; e += 64) {
      const int tl2 = e >> 4, sl = e & 15;
      float a = 0.f;
      if (sl <= tl2) {
        const u16* rp = &rB[(w * 16 + tl2) * 72];
        const u16* kp = &kB[(w * 16 + sl) * 72];
        const float* pp = (sl == tl2) ? uL : &Pt[tl2 - 1 - sl][0];
        #pragma unroll
        for (int i0 = 0; i0 < 64; i0 += 4) {
          u16x4 ra = *(const u16x4*)(rp + i0);
          u16x4 ka = *(const u16x4*)(kp + i0);
          f32x4 pa = *(const f32x4*)(pp + i0);
          #pragma unroll
          for (int di = 0; di < 4; di++)
            a = fmaf(bf2f(ra[di]) * bf2f(ka[di]), pa[di], a);
        }
      }
      aB[(w * 16 + tl2) * 72 + w * 16 + sl] = f2bf(a);
    }
  }
  __syncthreads();

  u16* Ktt = KhX;
  {
    const int ii = tid & 63, s0 = (tid >> 6) * 16;
    #pragma unroll
    for (int ds = 0; ds < 16; ds += 2) {
      float v0 = bf2f(kB[(s0 + ds) * 72 + ii]) * Pt[63 - (s0 + ds)][ii];
      float v1 = bf2f(kB[(s0 + ds + 1) * 72 + ii]) * Pt[63 - (s0 + ds + 1)][ii];
      u32 pk = ((u32)f2bf(v1) << 16) | f2bf(v0);
      *(u32*)&Ktt[ii * 72 + s0 + ds] = pk;
    }
  }
  __syncthreads();

  const int lr = lane & 15, kq = lane >> 4;
  {
    f32x4 yac[4] = {};
    #pragma unroll
    for (int kf2 = 0; kf2 < 2; kf2++) {
      bf16x8 af = *(const bf16x8*)&aB[(w * 16 + lr) * 72 + kf2 * 32 + kq * 8];
      #pragma unroll
      for (int nf = 0; nf < 4; nf++) {
        bf16x8 bf_ = *(const bf16x8*)&Vt[(nf * 16 + lr) * 72 + kf2 * 32 + kq * 8];
        yac[nf] = __builtin_amdgcn_mfma_f32_16x16x32_bf16(af, bf_, yac[nf], 0, 0, 0);
      }
    }
    float* Yp = Yb + (size_t)bid * 4096;
    #pragma unroll
    for (int nf = 0; nf < 4; nf++)
      #pragma unroll
      for (int reg = 0; reg < 4; reg++)
        Yp[(w * 16 + kq * 4 + reg) * 64 + nf * 16 + lr] = yac[nf][reg];

    f32x4 dac[4] = {};
    #pragma unroll
    for (int kf2 = 0; kf2 < 2; kf2++) {
      bf16x8 af = *(const bf16x8*)&Ktt[(w * 16 + lr) * 72 + kf2 * 32 + kq * 8];
      #pragma unroll
      for (int nf = 0; nf < 4; nf++) {
        bf16x8 bf_ = *(const bf16x8*)&Vt[(nf * 16 + lr) * 72 + kf2 * 32 + kq * 8];
        dac[nf] = __builtin_amdgcn_mfma_f32_16x16x32_bf16(af, bf_, dac[nf], 0, 0, 0);
      }
    }
    float* Dp = Db + (size_t)bid * 4096;
    #pragma unroll
    for (int nf = 0; nf < 4; nf++)
      #pragma unroll
      for (int reg = 0; reg < 4; reg++)
        Dp[(w * 16 + kq * 4 + reg) * 64 + nf * 16 + lr] = dac[nf][reg];
  }
}

__global__ __launch_bounds__(256)
void wkv_scan(const float* __restrict__ s0g, const float* __restrict__ td,
              const float* __restrict__ Db, u16* __restrict__ Sbb,
              float* __restrict__ sout) {
  const int bh = blockIdx.x, h = bh & 31;
  const int tid = threadIdx.x;
  const int i = tid >> 2, j0 = (tid & 3) * 16;
  float d = __expf(td[h * 64 + i]);
  float w64 = exp2f(-1.4426950408889634f * d * 64.f);
  f32x4 S[4];
  const float* sp = s0g + ((size_t)bh * 64 + i) * 64 + j0;
  #pragma unroll
  for (int q = 0; q < 4; q++) S[q] = *(const f32x4*)(sp + q * 4);
  for (int c = 0; c < NCH; c++) {
    u16* op = Sbb + ((size_t)(bh * 16 + c)) * 4096 + i * 64 + j0;
    u16x8 o0, o1;
    #pragma unroll
    for (int e = 0; e < 4; e++) { o0[e] = f2bf(S[0][e]); o0[4 + e] = f2bf(S[1][e]);
                                  o1[e] = f2bf(S[2][e]); o1[4 + e] = f2bf(S[3][e]); }
    *(u16x8*)op = o0; *(u16x8*)(op + 8) = o1;
    const float* dp = Db + ((size_t)(bh * 16 + c)) * 4096 + i * 64 + j0;
    #pragma unroll
    for (int q = 0; q < 4; q++) {
      f32x4 dv = *(const f32x4*)(dp + q * 4);
      #pragma unroll
      for (int e = 0; e < 4; e++) S[q][e] = fmaf(w64, S[q][e], dv[e]);
    }
  }
  float* fo = sout + ((size_t)bh * 64 + i) * 64 + j0;
  #pragma unroll
  for (int q = 0; q < 4; q++) *(f32x4*)(fo + q * 4) = S[q];
}

__global__ __launch_bounds__(256)
void wkv_post(const u16* __restrict__ Rtb, const u16* __restrict__ Sbb,
              const float* __restrict__ Yb, const u16* __restrict__ g,
              const float* __restrict__ gnw, const float* __restrict__ gnb,
              u16* __restrict__ xo) {
  __shared__ u16 Rt[64 * 72];
  __shared__ u16 St[64 * 72];
  __shared__ u16 xoL[64 * 72];
  const int tid = threadIdx.x, bid = blockIdx.x;
  const int bh = bid >> 4, c = bid & 15;
  const int b = bh >> 5, h = bh & 31;
  const int lane = tid & 63, w = tid >> 6;
  const int row = tid >> 2, col0 = (tid & 3) * 16;

  {
    const u16* rp = Rtb + (size_t)bid * 4096 + row * 64 + col0;
    u16x8 a0 = *(const u16x8*)rp, a1 = *(const u16x8*)(rp + 8);
    *(u16x8*)&Rt[row * 72 + col0] = a0; *(u16x8*)&Rt[row * 72 + col0 + 8] = a1;
  }
  {
    const u16* sp = Sbb + ((size_t)(bh * 16 + c)) * 4096 + row * 64 + col0;
    u16x8 s0 = *(const u16x8*)sp, s1 = *(const u16x8*)(sp + 8);
    #pragma unroll
    for (int e = 0; e < 8; e++) {
      St[(col0 + e) * 72 + row] = s0[e];
      St[(col0 + 8 + e) * 72 + row] = s1[e];
    }
  }
  const int lr = lane & 15, kq = lane >> 4;
  f32x4 acc[4];
  {
    const float* Yp = Yb + (size_t)bid * 4096;
    #pragma unroll
    for (int nf = 0; nf < 4; nf++)
      #pragma unroll
      for (int reg = 0; reg < 4; reg++)
        acc[nf][reg] = Yp[(w * 16 + kq * 4 + reg) * 64 + nf * 16 + lr];
  }
  __syncthreads();
  #pragma unroll
  for (int kf2 = 0; kf2 < 2; kf2++) {
    bf16x8 af = *(const bf16x8*)&Rt[(w * 16 + lr) * 72 + kf2 * 32 + kq * 8];
    #pragma unroll
    for (int nf = 0; nf < 4; nf++) {
      bf16x8 bf_ = *(const bf16x8*)&St[(nf * 16 + lr) * 72 + kf2 * 32 + kq * 8];
      acc[nf] = __builtin_amdgcn_mfma_f32_16x16x32_bf16(af, bf_, acc[nf], 0, 0, 0);
    }
  }
  #pragma unroll
  for (int reg = 0; reg < 4; reg++) {
    float s = 0.f, ss = 0.f;
    #pragma unroll
    for (int nf = 0; nf < 4; nf++) {
      float z = acc[nf][reg] * 0.125f;
      s += z; ss += z * z;
    }
    #pragma unroll
    for (int m = 1; m < 16; m <<= 1) { s += __shfl_xor(s, m); ss += __shfl_xor(ss, m); }
    float mean = s * (1.f / 64.f);
    float var = ss * (1.f / 64.f) - mean * mean;
    float inv = rsqrtf(var + 1e-5f);
    const int tau = w * 16 + kq * 4 + reg;
    #pragma unroll
    for (int nf = 0; nf < 4; nf++) {
      const int col = nf * 16 + lr;
      float z = acc[nf][reg] * 0.125f;
      float zn = (z - mean) * inv * gnw[h * 64 + col] + gnb[h * 64 + col];
      float gv = bf2f(g[((size_t)b * Tt + c * 64 + tau) * Cc + h * 64 + col]);
      xoL[tau * 72 + col] = f2bf(zn * gv);
    }
  }
  __syncthreads();
  {
    u16x8 o0 = *(const u16x8*)&xoL[row * 72 + col0];
    u16x8 o1 = *(const u16x8*)&xoL[row * 72 + col0 + 8];
    u16* xop = xo + ((size_t)b * Tt + c * 64 + row) * Cc + h * 64 + col0;
    *(u16x8*)xop = o0; *(u16x8*)(xop + 8) = o1;
  }
}

// ---------- orchestration ----------
extern "C" void kernel_launch(void* const* d_in, const int* in_sizes, int n_in,
                              void* d_out, int out_size, void* d_ws, size_t ws_size,
                              hipStream_t stream) {
  const float* x         = (const float*)d_in[0];
  const float* att_shift = (const float*)d_in[1];
  const float* wkv0      = (const float*)d_in[2];
  const float* ffn_shift = (const float*)d_in[3];
  const float* ln1w = (const float*)d_in[4];
  const float* ln1b = (const float*)d_in[5];
  const float* ln2w = (const float*)d_in[6];
  const float* ln2b = (const float*)d_in[7];
  const float* mixk = (const float*)d_in[8];
  const float* mixv = (const float*)d_in[9];
  const float* mixr = (const float*)d_in[10];
  const float* mixg = (const float*)d_in[11];
  const float* Wr = (const float*)d_in[12];
  const float* Wk = (const float*)d_in[13];
  const float* Wv = (const float*)d_in[14];
  const float* Wg = (const float*)d_in[15];
  const float* Wo = (const float*)d_in[16];
  const float* td = (const float*)d_in[17];
  const float* tf = (const float*)d_in[18];
  const float* gnw = (const float*)d_in[19];
  const float* gnb = (const float*)d_in[20];
  const float* cmk = (const float*)d_in[21];
  const float* cmr = (const float*)d_in[22];
  const float* Wck = (const float*)d_in[23];
  const float* Wcr = (const float*)d_in[24];
  const float* Wcv = (const float*)d_in[25];

  constexpr size_t SZ_CC = (size_t)Cc * Cc * 2;
  constexpr size_t SZ_CF = (size_t)Cc * FF * 2;
  constexpr size_t SZ_AB = (size_t)BT * Cc * 2;
  constexpr size_t O_W   = 0;
  constexpr size_t O_R1  = 6 * SZ_CC + 2 * SZ_CF;
  constexpr size_t R1_SZ = 4 * SZ_AB;
  constexpr size_t O_R2  = O_R1 + R1_SZ;
  constexpr size_t R2_SZ = 3 * SZ_AB;
  constexpr size_t O_R3  = O_R2 + R2_SZ;
  constexpr size_t WS_NEED = O_R3 + SZ_AB;

  if (ws_size < WS_NEED) return;

  char* ws = (char*)d_ws;
  u16* WrT  = (u16*)(ws + O_W);
  u16* WkT  = (u16*)(ws + O_W + 1 * SZ_CC);
  u16* WvT  = (u16*)(ws + O_W + 2 * SZ_CC);
  u16* WgT  = (u16*)(ws + O_W + 3 * SZ_CC);
  u16* WoT  = (u16*)(ws + O_W + 4 * SZ_CC);
  u16* WcrT = (u16*)(ws + O_W + 5 * SZ_CC);
  u16* WckT = (u16*)(ws + O_W + 6 * SZ_CC);
  u16* WcvT = (u16*)(ws + O_W + 6 * SZ_CC + SZ_CF);

  u16*   xk  = (u16*)(ws + O_R1);
  u16*   xv  = (u16*)(ws + O_R1 + SZ_AB);
  u16*   xr  = (u16*)(ws + O_R1 + 2 * SZ_AB);
  u16*   xg  = (u16*)(ws + O_R1 + 3 * SZ_AB);
  float* Yb  = (float*)(ws + O_R1);
  u16*   Rtb = (u16*)(ws + O_R1 + 2 * SZ_AB);
  u16*   Sbb = (u16*)(ws + O_R1 + 3 * SZ_AB);
  u16*   kk  = (u16*)(ws + O_R1);
  u16*   rb  = (u16*)(ws + O_R2);
  u16*   kb  = (u16*)(ws + O_R2 + SZ_AB);
  u16*   vb  = (u16*)(ws + O_R2 + 2 * SZ_AB);
  u16*   xcr = (u16*)(ws + O_R2);
  u16*   xck = (u16*)(ws + O_R2 + SZ_AB);
  u16*   xo  = (u16*)(ws + O_R2 + 2 * SZ_AB);
  float* kv0 = (float*)(ws + O_R2 + SZ_AB);
  u16*   gbuf = (u16*)(ws + O_R3);
  u16*   kv1  = (u16*)(ws + O_R3);

  float* out      = (float*)d_out;
  float* x1_last  = out + (size_t)BT * Cc;
  float* wkv_out  = x1_last + (size_t)Bb * Cc;
  float* x2_last  = wkv_out + (size_t)Bb * Hh * Nd * Nd;
  float* Db       = out;  // free until Wo-gemm; scan consumes it first

  transp64_6cc<<<dim3(32, 32, 6), 256, 0, stream>>>(Wr, Wk, Wv, Wg, Wo, Wcr,
                                                    WrT, WkT, WvT, WgT, WoT, WcrT);
  transp64<<<dim3(112, 32), 256, 0, stream>>>(Wck, WckT, Cc, FF);
  transp64<<<dim3(32, 112), 256, 0, stream>>>(Wcv, WcvT, FF, Cc);

  ln_mix4<<<BT, 256, 0, stream>>>(x, att_shift, ln1w, ln1b,
                                  mixk, mixv, mixr, mixg, xk, xv, xr, xg, x1_last);
  gemm256_proj<<<512, 512, 0, stream>>>(xr, xk, xv, xg,
                                        WrT, WkT, WvT, WgT,
                                        rb, kb, vb, gbuf);
  wkv_pre<<<Bb * Hh * NCH, 256, 0, stream>>>(rb, kb, vb, td, tf, Yb, Db, Rtb);
  wkv_scan<<<Bb * Hh, 256, 0, stream>>>(wkv0, td, Db, Sbb, wkv_out);
  wkv_post<<<Bb * Hh * NCH, 256, 0, stream>>>(Rtb, Sbb, Yb, gbuf, gnw, gnb, xo);
  gemm128s<4><<<256, 512, 0, stream>>>(xo, WoT, Cc, Cc, out, nullptr, x,
                                       nullptr, nullptr, 16);
  ln_mix2<<<BT, 256, 0, stream>>>(out, ffn_shift, ln2w, ln2b, cmk, cmr, xck, xcr, x2_last);
  gemm256s<3><<<448, 512, 0, stream>>>(xck, WckT, FF, Cc, nullptr, kk, nullptr, 28);
  gemm256_splitk<<<256, 512, 0, stream>>>(kk, WcvT, kv0, kv1);
  gemm128s<6><<<256, 512, 0, stream>>>(xcr, WcrT, Cc, Cc, out, nullptr, out,
                                       kv0, kv1, 16);

  (void)in_sizes; (void)n_in; (void)out_size;
}